// Round 1
// baseline (564.885 us; speedup 1.0000x reference)
//
#include <hip/hip_runtime.h>
#include <stdint.h>

#define NCLS 80
#define TOPK 200
#define CONF_T 0.05f
#define NMS_T 0.5f
#define CROPF 300.0f
#define NA 49104
#define NB 8
#define NSEL 512
#define MKEYS 2048

__device__ __forceinline__ void decode_box(const float4 rg, const float4 an,
                                           float& x1, float& y1, float& x2, float& y2) {
    // anchors: (ymin, xmin, ymax, xmax); reg: (dy, dx, dh, dw)
    float yca = (an.x + an.z) * 0.5f;
    float xca = (an.y + an.w) * 0.5f;
    float ha = an.z - an.x;
    float wa = an.w - an.y;
    float w = expf(rg.w) * wa;
    float h = expf(rg.z) * ha;
    float yc = rg.x * ha + yca;
    float xc = rg.y * wa + xca;
    x1 = fmaxf(xc - w * 0.5f, 0.0f) / CROPF;
    y1 = fmaxf(yc - h * 0.5f, 0.0f) / CROPF;
    x2 = fminf(xc + w * 0.5f, CROPF - 1.0f) / CROPF;
    y2 = fminf(yc + h * 0.5f, CROPF - 1.0f) / CROPF;
}

// Phase 1: 4 lanes per anchor. Max/argmax over classes 1..80 (skip background 0),
// sigmoid score, class byte, box-coordinate max for the per-image offset factor.
__global__ __launch_bounds__(256) void phase1_kernel(
    const float* __restrict__ conf, const float* __restrict__ reg,
    const float* __restrict__ anch, float* __restrict__ scores,
    unsigned char* __restrict__ cls, int* __restrict__ maxbox)
{
    int tid = blockIdx.x * 256 + threadIdx.x;
    int quad = tid >> 2;   // global anchor index b*NA + a
    int sub = tid & 3;
    if (quad >= NB * NA) return;

    const float* crow = conf + (size_t)quad * (NCLS + 1);
    float best = -3.0e38f; int bc = 255;
    for (int c = sub; c <= NCLS; c += 4) {
        if (c == 0) continue;          // background stripped
        float v = crow[c];
        if (v > best) { best = v; bc = c; }   // strict > : first-index tie-break
    }
    // reduce across the 4 lanes of the quad (tie -> smaller class index)
    for (int m = 1; m <= 2; m <<= 1) {
        float ov = __shfl_xor(best, m);
        int oc = __shfl_xor(bc, m);
        if (ov > best || (ov == best && oc < bc)) { best = ov; bc = oc; }
    }
    float bmax = 0.0f;   // x1,y1 >= 0 always, so 0 is a safe identity
    if (sub == 0) {
        int a = quad % NA;
        float4 rg = reinterpret_cast<const float4*>(reg)[quad];
        float4 an = reinterpret_cast<const float4*>(anch)[a];
        float x1, y1, x2, y2; decode_box(rg, an, x1, y1, x2, y2);
        bmax = fmaxf(fmaxf(x1, y1), fmaxf(x2, y2));
        scores[quad] = 1.0f / (1.0f + expf(-best));
        cls[quad] = (unsigned char)(bc - 1);
    }
    for (int m = 1; m < 64; m <<= 1) bmax = fmaxf(bmax, __shfl_xor(bmax, m));
    if ((threadIdx.x & 63) == 0) {
        int b = quad / NA;   // a wave never straddles images (NA % 16 == 0)
        atomicMax(&maxbox[b], __float_as_int(bmax));  // all values >= 0
    }
}

__device__ __forceinline__ bool iou_gt(const float4 kb, float bx1, float by1,
                                       float bx2, float by2, float areaB) {
    float ix1 = fmaxf(bx1, kb.x), iy1 = fmaxf(by1, kb.y);
    float ix2 = fminf(bx2, kb.z), iy2 = fminf(by2, kb.w);
    float inter = fmaxf(ix2 - ix1, 0.0f) * fmaxf(iy2 - iy1, 0.0f);
    float areaK = (kb.z - kb.x) * (kb.w - kb.y);
    float uni = areaB + areaK - inter;
    float iou = (uni > 0.0f) ? (inter / uni) : 0.0f;
    return iou > NMS_T;
}

// Phase 2: one block per image. Exact two-level radix-select of the top >=NSEL
// candidates by f32 score bits, bitonic sort of (score_bits, ~index) keys,
// then exact greedy NMS (wave 0) with kept offset-boxes in registers.
__global__ __launch_bounds__(1024) void phase2_kernel(
    const float* __restrict__ reg, const float* __restrict__ anch,
    const float* __restrict__ scores, const unsigned char* __restrict__ cls,
    const int* __restrict__ maxbox, float* __restrict__ out)
{
    __shared__ uint32_t hist[8192];     // coarse: score_bits >> 17
    __shared__ uint32_t fhist[2048];    // fine:   (score_bits >> 6) & 2047 within coarse bin
    __shared__ uint32_t csum[1024];
    __shared__ unsigned long long keys[MKEYS];
    __shared__ uint32_t ccount[NCLS];
    __shared__ uint32_t shv[8];         // 0:cbin 1:above 2:found 3:T 4:nGather

    const int b = blockIdx.x;
    const int t = threadIdx.x;
    const float* sc = scores + (size_t)b * NA;

    for (int i = t; i < 8192; i += 1024) hist[i] = 0;
    for (int i = t; i < 2048; i += 1024) fhist[i] = 0;
    for (int i = t; i < MKEYS; i += 1024) keys[i] = 0ULL;
    if (t < NCLS) ccount[t] = 0;
    if (t < 8) shv[t] = 0;
    __syncthreads();

    // coarse histogram (valid = score > CONF_T, exactly as reference)
    for (int g = t; g < NA; g += 1024) {
        float s = sc[g];
        if (s > CONF_T) atomicAdd(&hist[__float_as_uint(s) >> 17], 1u);
    }
    __syncthreads();
    { uint32_t s8 = 0;
      #pragma unroll
      for (int k = 0; k < 8; ++k) s8 += hist[t * 8 + k];
      csum[t] = s8; }
    __syncthreads();
    if (t == 0) {
        uint32_t run = 0, above = 0; int chunk = -1;
        for (int i = 1023; i >= 0; --i) {   // no break: lets loads pipeline
            uint32_t v = csum[i];
            if (chunk < 0 && run + v >= NSEL) { chunk = i; above = run; }
            run += v;
        }
        if (chunk >= 0) {
            uint32_t run2 = above, ab = 0; int cb = -1;
            for (int k = 7; k >= 0; --k) {
                uint32_t v = hist[chunk * 8 + k];
                if (cb < 0 && run2 + v >= NSEL) { cb = chunk * 8 + k; ab = run2; }
                run2 += v;
            }
            shv[0] = (uint32_t)cb; shv[1] = ab; shv[2] = 1;
        } else { shv[2] = 0; shv[3] = 0; }   // fewer than NSEL valid: take all
    }
    __syncthreads();
    uint32_t cbin = shv[0];
    if (shv[2]) {
        for (int g = t; g < NA; g += 1024) {
            float s = sc[g];
            if (s > CONF_T) {
                uint32_t bits = __float_as_uint(s);
                if ((bits >> 17) == cbin) atomicAdd(&fhist[(bits >> 6) & 2047u], 1u);
            }
        }
    }
    __syncthreads();
    csum[t] = fhist[t * 2] + fhist[t * 2 + 1];
    __syncthreads();
    if (t == 0 && shv[2]) {
        uint32_t run = shv[1], above2 = 0; int chunk = -1;
        for (int i = 1023; i >= 0; --i) {
            uint32_t v = csum[i];
            if (chunk < 0 && run + v >= NSEL) { chunk = i; above2 = run; }
            run += v;
        }
        uint32_t fbin = 0;
        if (chunk >= 0) {
            uint32_t v1 = fhist[chunk * 2 + 1];
            fbin = (above2 + v1 >= NSEL) ? (uint32_t)(chunk * 2 + 1) : (uint32_t)(chunk * 2);
        }
        shv[3] = (cbin << 11) | fbin;   // threshold on (bits >> 6)
    }
    __syncthreads();
    uint32_t T = shv[3];
    for (int g = t; g < NA; g += 1024) {
        float s = sc[g];
        if (s > CONF_T) {
            uint32_t bits = __float_as_uint(s);
            if ((bits >> 6) >= T) {
                uint32_t pos = atomicAdd(&shv[4], 1u);
                if (pos < MKEYS)
                    keys[pos] = ((unsigned long long)bits << 32) |
                                (unsigned long long)(0xFFFFFFFFu - (uint32_t)g);
            }
        }
    }
    __syncthreads();
    uint32_t nG = shv[4]; if (nG > MKEYS) nG = MKEYS;

    // bitonic sort, descending (padding zeros sink to the end)
    for (uint32_t k = 2; k <= MKEYS; k <<= 1) {
        for (uint32_t j = k >> 1; j > 0; j >>= 1) {
            #pragma unroll
            for (int e = 0; e < 2; ++e) {
                uint32_t i = t + (uint32_t)e * 1024u;
                uint32_t ixj = i ^ j;
                if (ixj > i) {
                    unsigned long long a = keys[i], bb = keys[ixj];
                    bool doswap = ((i & k) == 0) ? (a < bb) : (a > bb);
                    if (doswap) { keys[i] = bb; keys[ixj] = a; }
                }
            }
            __syncthreads();
        }
    }
    __syncthreads();

    if (t >= 64) return;   // NMS is wave 0 only; no barriers beyond this point
    const int lane = t;
    const float offmul = __int_as_float(maxbox[b]) + 1.0f;   // jnp.max(boxes)+1
    int keptn = 0;
    float4 kb0 = {0,0,0,0}, kb1 = {0,0,0,0}, kb2 = {0,0,0,0}, kb3 = {0,0,0,0};

    for (uint32_t base = 0; base < nG && keptn < TOPK; base += 64) {
        uint32_t ci = base + (uint32_t)lane;
        float x1 = 0, y1 = 0, x2 = 0, y2 = 0, sscore = 0;
        float o1 = 0, o2 = 0, o3 = 0, o4 = 0;
        int ccls = 0;
        if (ci < nG) {
            unsigned long long key = keys[ci];
            uint32_t g = 0xFFFFFFFFu - (uint32_t)(key & 0xFFFFFFFFull);
            sscore = __uint_as_float((uint32_t)(key >> 32));
            size_t qi = (size_t)b * NA + g;
            ccls = (int)cls[qi];
            float4 rg = reinterpret_cast<const float4*>(reg)[qi];
            float4 an = reinterpret_cast<const float4*>(anch)[g];
            decode_box(rg, an, x1, y1, x2, y2);
            float off = (float)ccls * offmul;
            o1 = x1 + off; o2 = y1 + off; o3 = x2 + off; o4 = y2 + off;
        }
        uint32_t nb = nG - base; if (nb > 64u) nb = 64u;
        for (uint32_t i = 0; i < nb && keptn < TOPK; ++i) {
            float bx1 = __shfl(o1, (int)i), by1 = __shfl(o2, (int)i);
            float bx2 = __shfl(o3, (int)i), by2 = __shfl(o4, (int)i);
            float areaB = (bx2 - bx1) * (by2 - by1);
            bool sup = false;
            if (lane       < keptn) sup = sup || iou_gt(kb0, bx1, by1, bx2, by2, areaB);
            if (lane + 64  < keptn) sup = sup || iou_gt(kb1, bx1, by1, bx2, by2, areaB);
            if (lane + 128 < keptn) sup = sup || iou_gt(kb2, bx1, by1, bx2, by2, areaB);
            if (lane + 192 < keptn) sup = sup || iou_gt(kb3, bx1, by1, bx2, by2, areaB);
            if (__ballot(sup) == 0ull) {
                float rx1 = __shfl(x1, (int)i), ry1 = __shfl(y1, (int)i);
                float rx2 = __shfl(x2, (int)i), ry2 = __shfl(y2, (int)i);
                float rsc = __shfl(sscore, (int)i);
                int rcl = __shfl(ccls, (int)i);
                if (lane == (keptn & 63)) {
                    float4 nbx = make_float4(bx1, by1, bx2, by2);
                    switch (keptn >> 6) {
                        case 0: kb0 = nbx; break;
                        case 1: kb1 = nbx; break;
                        case 2: kb2 = nbx; break;
                        default: kb3 = nbx; break;
                    }
                }
                if (lane == 0) {
                    uint32_t slot = ccount[rcl]; ccount[rcl] = slot + 1;
                    float* o = out + ((((size_t)b * (NCLS + 1)) + (size_t)(rcl + 1)) * TOPK + slot) * 5;
                    o[0] = rsc; o[1] = rx1; o[2] = ry1; o[3] = rx2; o[4] = ry2;
                }
                ++keptn;
            }
        }
    }
}

extern "C" void kernel_launch(void* const* d_in, const int* in_sizes, int n_in,
                              void* d_out, int out_size, void* d_ws, size_t ws_size,
                              hipStream_t stream)
{
    const float* conf = (const float*)d_in[0];   // [B, A, 81] f32
    const float* reg  = (const float*)d_in[1];   // [B, A, 4]  f32
    const float* anch = (const float*)d_in[2];   // [A, 4]     f32
    float* out = (float*)d_out;                  // [B, 81, 200, 5] f32

    char* ws = (char*)d_ws;
    int* maxbox = (int*)ws;                                      // 8 ints, padded to 256B
    float* scores = (float*)(ws + 256);                          // NB*NA f32
    unsigned char* cls = (unsigned char*)(ws + 256 + (size_t)NB * NA * 4);  // NB*NA u8

    hipMemsetAsync(d_out, 0, (size_t)out_size * sizeof(float), stream);
    hipMemsetAsync(maxbox, 0, 256, stream);

    int quads = NB * NA;                 // 392832
    int blocks = (quads * 4) / 256;      // 6138 exact
    phase1_kernel<<<blocks, 256, 0, stream>>>(conf, reg, anch, scores, cls, maxbox);
    phase2_kernel<<<NB, 1024, 0, stream>>>(reg, anch, scores, cls, maxbox, out);
}

// Round 2
// 438.404 us; speedup vs baseline: 1.2885x; 1.2885x over previous
//
#include <hip/hip_runtime.h>
#include <stdint.h>

#define NCLS 80
#define TOPK 200
#define CONF_T 0.05f
#define CROPF 300.0f
#define NA 49104
#define NB 8
#define NSEL 512
#define MKEYS 2048
#define APB 64
#define CHUNK (APB * 81)

__device__ __forceinline__ void decode_box(const float4 rg, const float4 an,
                                           float& x1, float& y1, float& x2, float& y2) {
    // anchors: (ymin, xmin, ymax, xmax); reg: (dy, dx, dh, dw)
    float yca = (an.x + an.z) * 0.5f;
    float xca = (an.y + an.w) * 0.5f;
    float ha = an.z - an.x;
    float wa = an.w - an.y;
    float w = expf(rg.w) * wa;
    float h = expf(rg.z) * ha;
    float yc = rg.x * ha + yca;
    float xc = rg.y * wa + xca;
    x1 = fmaxf(xc - w * 0.5f, 0.0f) / CROPF;
    y1 = fmaxf(yc - h * 0.5f, 0.0f) / CROPF;
    x2 = fminf(xc + w * 0.5f, CROPF - 1.0f) / CROPF;
    y2 = fminf(yc + h * 0.5f, CROPF - 1.0f) / CROPF;
}

// Phase 1: LDS-staged, coalesced float4 reads of conf. 64 anchors/block,
// 4 lanes per anchor for the class argmax (identical tie-break to validated r1).
__global__ __launch_bounds__(256) void phase1_kernel(
    const float* __restrict__ conf, const float* __restrict__ reg,
    const float* __restrict__ anch, float* __restrict__ scores,
    unsigned char* __restrict__ cls, int* __restrict__ maxbox)
{
    __shared__ float lds[CHUNK];
    const int blk = blockIdx.x, t = threadIdx.x;
    const float4* src = reinterpret_cast<const float4*>(conf + (size_t)blk * CHUNK);
    float4* dst = reinterpret_cast<float4*>(lds);
    for (int i = t; i < CHUNK / 4; i += 256) dst[i] = src[i];
    __syncthreads();

    const int la = t >> 2, sub = t & 3;
    const int quad = blk * APB + la;           // global anchor b*NA + a
    const float* crow = lds + la * 81;
    float best = -3.0e38f; int bc = 255;
    for (int c = sub; c <= NCLS; c += 4) {
        if (c == 0) continue;                  // background stripped
        float v = crow[c];
        if (v > best) { best = v; bc = c; }    // strict > : first-index tie-break
    }
    for (int m = 1; m <= 2; m <<= 1) {
        float ov = __shfl_xor(best, m);
        int oc = __shfl_xor(bc, m);
        if (ov > best || (ov == best && oc < bc)) { best = ov; bc = oc; }
    }
    float bmax = 0.0f;
    if (sub == 0) {
        int a = quad % NA;
        float4 rg = reinterpret_cast<const float4*>(reg)[quad];
        float4 an = reinterpret_cast<const float4*>(anch)[a];
        float x1, y1, x2, y2; decode_box(rg, an, x1, y1, x2, y2);
        bmax = fmaxf(fmaxf(x1, y1), fmaxf(x2, y2));
        scores[quad] = 1.0f / (1.0f + expf(-best));
        cls[quad] = (unsigned char)(bc - 1);
    }
    for (int m = 1; m < 64; m <<= 1) bmax = fmaxf(bmax, __shfl_xor(bmax, m));
    if ((t & 63) == 0) {
        int b = quad / NA;                     // NA % 16 == 0: waves never straddle images
        atomicMax(&maxbox[b], __float_as_int(bmax));
    }
}

// block-wide inclusive SUFFIX scan over 1024 values; result into outarr[t].
__device__ __forceinline__ void suffix_scan_1024(uint32_t v, int t,
                                                 uint32_t* wtot, uint32_t* outarr) {
    uint32_t r = v;
    const int lane = t & 63, w = t >> 6;
    #pragma unroll
    for (int m = 1; m < 64; m <<= 1) {
        uint32_t o = __shfl_down(r, m);
        if (lane + m < 64) r += o;
    }
    if (lane == 0) wtot[w] = r;
    __syncthreads();
    if (t < 16) {
        uint32_t v0 = wtot[t], x = v0;
        #pragma unroll
        for (int m = 1; m < 16; m <<= 1) {
            uint32_t o = __shfl_down(x, m);
            if (t + m < 16) x += o;
        }
        wtot[t] = x - v0;                      // exclusive suffix of wave totals
    }
    __syncthreads();
    outarr[t] = r + wtot[w];
    __syncthreads();
}

// Phase 2: one block/image. Radix-select top >=NSEL, bitonic sort, 512x512
// suppression-mask NMS (exact greedy), serial fallback past 512.
__global__ __launch_bounds__(1024) void phase2_kernel(
    const float* __restrict__ reg, const float* __restrict__ anch,
    const float* __restrict__ scores, const unsigned char* __restrict__ cls,
    const int* __restrict__ maxbox, float* __restrict__ out)
{
    __shared__ uint64_t s_mask[4096];      // 32KB  alias: hist u32[8192]
    __shared__ float4   s_boxo[512];       // 8KB   alias: fhist u32[2048]
    __shared__ uint64_t s_keys[MKEYS];     // 16KB  alias: csum u32[1024] (first 4KB)
    __shared__ float4   s_keptbox[TOPK];   // 3.2KB
    __shared__ float    s_areao[512];      // 2KB
    __shared__ uint32_t s_ccount[NCLS];
    __shared__ uint32_t s_kinfo[TOPK];
    __shared__ uint32_t s_wtot[16];
    __shared__ uint32_t s_shv[8];
    __shared__ uint8_t  s_clsl[512];

    uint32_t* hist  = (uint32_t*)s_mask;
    uint32_t* fhist = (uint32_t*)s_boxo;
    uint32_t* csum  = (uint32_t*)s_keys;

    const int b = blockIdx.x;
    const int t = threadIdx.x;
    const float* sc = scores + (size_t)b * NA;

    // ---- init
    for (int i = t; i < 8192; i += 1024) hist[i] = 0;
    if (t < NCLS) s_ccount[t] = 0;
    if (t < 8) s_shv[t] = 0;
    __syncthreads();

    // ---- coarse histogram (bits>>17)
    for (int g = t; g < NA; g += 1024) {
        float s = sc[g];
        if (s > CONF_T) atomicAdd(&hist[__float_as_uint(s) >> 17], 1u);
    }
    __syncthreads();

    // ---- coarse crossing via parallel suffix scan over 1024 chunk-sums
    uint32_t v8 = 0;
    #pragma unroll
    for (int k = 0; k < 8; ++k) v8 += hist[t * 8 + k];
    suffix_scan_1024(v8, t, s_wtot, csum);
    {
        uint32_t sIn = csum[t];
        uint32_t sNext = (t == 1023) ? 0u : csum[t + 1];
        if (sIn >= NSEL && sNext < NSEL) { s_shv[0] = (uint32_t)t; s_shv[1] = sNext; s_shv[2] = 1; }
    }
    __syncthreads();
    // zero fhist; t0 resolves coarse bin within the chunk (8 iters)
    for (int i = t; i < 2048; i += 1024) fhist[i] = 0;
    if (t == 0 && s_shv[2]) {
        uint32_t chunk = s_shv[0], run2 = s_shv[1], ab = 0; int cb = -1;
        for (int k = 7; k >= 0; --k) {
            uint32_t v = hist[chunk * 8 + k];
            if (cb < 0 && run2 + v >= NSEL) { cb = (int)(chunk * 8 + k); ab = run2; }
            run2 += v;
        }
        s_shv[0] = (uint32_t)cb; s_shv[1] = ab;
    }
    __syncthreads();

    const uint32_t found = s_shv[2], cbin = s_shv[0], above = s_shv[1];
    // ---- fine histogram ((bits>>6)&2047 within coarse bin)
    if (found) {
        for (int g = t; g < NA; g += 1024) {
            float s = sc[g];
            if (s > CONF_T) {
                uint32_t bits = __float_as_uint(s);
                if ((bits >> 17) == cbin) atomicAdd(&fhist[(bits >> 6) & 2047u], 1u);
            }
        }
    }
    __syncthreads();
    uint32_t fv = fhist[2 * t] + fhist[2 * t + 1];
    suffix_scan_1024(fv, t, s_wtot, csum);
    if (found) {
        uint32_t sIn = csum[t] + above;
        uint32_t sNext = ((t == 1023) ? 0u : csum[t + 1]) + above;
        if (sIn >= NSEL && sNext < NSEL) { s_shv[5] = (uint32_t)t; s_shv[6] = sNext; }
    }
    __syncthreads();
    if (t == 0) {
        if (found) {
            uint32_t pc = s_shv[5], ab2 = s_shv[6];
            uint32_t v1 = fhist[pc * 2 + 1];
            uint32_t fbin = (ab2 + v1 >= NSEL) ? (pc * 2 + 1) : (pc * 2);
            s_shv[3] = (cbin << 11) | fbin;
        } else s_shv[3] = 0;
    }
    __syncthreads();

    // ---- gather candidates (score bits >> 6) >= T   (csum dead; zero keys)
    const uint32_t T = s_shv[3];
    for (int i = t; i < MKEYS; i += 1024) s_keys[i] = 0ull;
    __syncthreads();
    for (int g = t; g < NA; g += 1024) {
        float s = sc[g];
        if (s > CONF_T) {
            uint32_t bits = __float_as_uint(s);
            if ((bits >> 6) >= T) {
                uint32_t pos = atomicAdd(&s_shv[4], 1u);
                if (pos < MKEYS)
                    s_keys[pos] = ((uint64_t)bits << 32) |
                                  (uint64_t)(0xFFFFFFFFu - (uint32_t)g);
            }
        }
    }
    __syncthreads();

    uint32_t nG = s_shv[4]; if (nG > MKEYS) nG = MKEYS;
    uint32_t SS = 512; while (SS < nG) SS <<= 1;

    // ---- bitonic sort descending over SS (padding zeros sink)
    for (uint32_t k = 2; k <= SS; k <<= 1) {
        for (uint32_t j = k >> 1; j > 0; j >>= 1) {
            for (uint32_t i = t; i < SS; i += 1024) {
                uint32_t ixj = i ^ j;
                if (ixj > i) {
                    uint64_t a = s_keys[i], bb2 = s_keys[ixj];
                    bool sw = ((i & k) == 0) ? (a < bb2) : (a > bb2);
                    if (sw) { s_keys[i] = bb2; s_keys[ixj] = a; }
                }
            }
            __syncthreads();
        }
    }

    // ---- prep first 512: offset boxes, areas, classes  (fhist dead)
    const float offm = __int_as_float(maxbox[b]) + 1.0f;
    if (t < 512) {
        if ((uint32_t)t < nG) {
            uint64_t key = s_keys[t];
            uint32_t g = 0xFFFFFFFFu - (uint32_t)key;
            size_t qi = (size_t)b * NA + g;
            int c = (int)cls[qi];
            s_clsl[t] = (uint8_t)c;
            float4 rg = reinterpret_cast<const float4*>(reg)[qi];
            float4 an = reinterpret_cast<const float4*>(anch)[g];
            float x1, y1, x2, y2; decode_box(rg, an, x1, y1, x2, y2);
            float off = (float)c * offm;
            float4 bo = make_float4(x1 + off, y1 + off, x2 + off, y2 + off);
            s_boxo[t] = bo;
            s_areao[t] = (bo.z - bo.x) * (bo.w - bo.y);
        } else {
            s_clsl[t] = 0;
            s_boxo[t] = make_float4(0.f, 0.f, 0.f, 0.f);
            s_areao[t] = 0.f;
        }
    }
    __syncthreads();

    // ---- suppression mask: mask[w*512+i] = cols [64w,64w+64) of row i  (hist dead)
    {
        const int i = t & 511;
        const float4 bi = s_boxo[i];
        const float aI = s_areao[i];
        for (int w = (t >> 9); w < 8; w += 2) {
            uint64_t m = 0ull;
            for (int jj = 0; jj < 64; ++jj) {
                float4 bj = s_boxo[w * 64 + jj];       // wave-broadcast read
                float ix1 = fmaxf(bi.x, bj.x), iy1 = fmaxf(bi.y, bj.y);
                float ix2 = fminf(bi.z, bj.z), iy2 = fminf(bi.w, bj.w);
                float inter = fmaxf(ix2 - ix1, 0.f) * fmaxf(iy2 - iy1, 0.f);
                float uni = aI + s_areao[w * 64 + jj] - inter;
                if (uni > 0.f && inter + inter > uni) m |= (1ull << jj);
            }
            s_mask[(size_t)w * 512 + i] = m;
        }
    }
    __syncthreads();

    // ---- exact greedy scan (t0): pure bitmask ops
    if (t == 0) {
        uint64_t alive[8];
        #pragma unroll
        for (int w = 0; w < 8; ++w) alive[w] = ~0ull;
        int nk = 0;
        int lim = (nG < 512u) ? (int)nG : 512;
        for (int i = 0; i < lim && nk < TOPK; ++i) {
            if ((alive[i >> 6] >> (i & 63)) & 1ull) {
                int c = (int)s_clsl[i];
                uint32_t slot = s_ccount[c]; s_ccount[c] = slot + 1;
                s_kinfo[nk] = (uint32_t)i | (slot << 11) | ((uint32_t)c << 19);
                s_keptbox[nk] = s_boxo[i];
                ++nk;
                #pragma unroll
                for (int w = 0; w < 8; ++w) alive[w] &= ~s_mask[(size_t)w * 512 + i];
            }
        }
        // fallback past 512 (exactness insurance; ~never taken)
        if (nk < TOPK && nG > 512u) {
            for (uint32_t ci = 512; ci < nG && nk < TOPK; ++ci) {
                uint64_t key = s_keys[ci];
                uint32_t g = 0xFFFFFFFFu - (uint32_t)key;
                size_t qi = (size_t)b * NA + g;
                int c = (int)cls[qi];
                float4 rg = reinterpret_cast<const float4*>(reg)[qi];
                float4 an = reinterpret_cast<const float4*>(anch)[g];
                float x1, y1, x2, y2; decode_box(rg, an, x1, y1, x2, y2);
                float off = (float)c * offm;
                float4 bo = make_float4(x1 + off, y1 + off, x2 + off, y2 + off);
                float aB2 = (bo.z - bo.x) * (bo.w - bo.y);
                bool sup = false;
                for (int k2 = 0; k2 < nk && !sup; ++k2) {
                    float4 kb = s_keptbox[k2];
                    float aK = (kb.z - kb.x) * (kb.w - kb.y);
                    float ix1 = fmaxf(bo.x, kb.x), iy1 = fmaxf(bo.y, kb.y);
                    float ix2 = fminf(bo.z, kb.z), iy2 = fminf(bo.w, kb.w);
                    float inter = fmaxf(ix2 - ix1, 0.f) * fmaxf(iy2 - iy1, 0.f);
                    float uni = aB2 + aK - inter;
                    sup = (uni > 0.f && inter + inter > uni);
                }
                if (!sup) {
                    uint32_t slot = s_ccount[c]; s_ccount[c] = slot + 1;
                    s_kinfo[nk] = ci | (slot << 11) | ((uint32_t)c << 19);
                    s_keptbox[nk] = bo;
                    ++nk;
                }
            }
        }
        s_shv[7] = (uint32_t)nk;
    }
    __syncthreads();

    // ---- parallel output
    uint32_t nk = s_shv[7];
    if ((uint32_t)t < nk) {
        uint32_t info = s_kinfo[t];
        uint32_t i = info & 2047u;
        uint32_t slot = (info >> 11) & 255u;
        uint32_t c = (info >> 19) & 127u;
        uint64_t key = s_keys[i];
        uint32_t g = 0xFFFFFFFFu - (uint32_t)key;
        float scv = __uint_as_float((uint32_t)(key >> 32));
        size_t qi = (size_t)b * NA + g;
        float4 rg = reinterpret_cast<const float4*>(reg)[qi];
        float4 an = reinterpret_cast<const float4*>(anch)[g];
        float x1, y1, x2, y2; decode_box(rg, an, x1, y1, x2, y2);
        float* o = out + (((size_t)b * (NCLS + 1) + (size_t)(c + 1)) * TOPK + slot) * 5;
        o[0] = scv; o[1] = x1; o[2] = y1; o[3] = x2; o[4] = y2;
    }
}

extern "C" void kernel_launch(void* const* d_in, const int* in_sizes, int n_in,
                              void* d_out, int out_size, void* d_ws, size_t ws_size,
                              hipStream_t stream)
{
    const float* conf = (const float*)d_in[0];   // [B, A, 81] f32
    const float* reg  = (const float*)d_in[1];   // [B, A, 4]  f32
    const float* anch = (const float*)d_in[2];   // [A, 4]     f32
    float* out = (float*)d_out;                  // [B, 81, 200, 5] f32

    char* ws = (char*)d_ws;
    int* maxbox = (int*)ws;                                                 // 8 ints
    float* scores = (float*)(ws + 256);                                     // NB*NA f32
    unsigned char* cls = (unsigned char*)(ws + 256 + (size_t)NB * NA * 4);  // NB*NA u8

    hipMemsetAsync(d_out, 0, (size_t)out_size * sizeof(float), stream);
    hipMemsetAsync(maxbox, 0, 256, stream);

    int blocks = (NB * NA) / APB;        // 6138 exact
    phase1_kernel<<<blocks, 256, 0, stream>>>(conf, reg, anch, scores, cls, maxbox);
    phase2_kernel<<<NB, 1024, 0, stream>>>(reg, anch, scores, cls, maxbox, out);
}

// Round 3
// 215.630 us; speedup vs baseline: 2.6197x; 2.0331x over previous
//
#include <hip/hip_runtime.h>
#include <stdint.h>

#define NCLS 80
#define TOPK 200
#define CONF_T 0.05f
#define CROPF 300.0f
#define NA 49104
#define NB 8
#define NSEL 512
#define MKEYS 2048
#define APB 64
#define CHUNK (APB * 81)

__device__ __forceinline__ void decode_box(const float4 rg, const float4 an,
                                           float& x1, float& y1, float& x2, float& y2) {
    // anchors: (ymin, xmin, ymax, xmax); reg: (dy, dx, dh, dw)
    float yca = (an.x + an.z) * 0.5f;
    float xca = (an.y + an.w) * 0.5f;
    float ha = an.z - an.x;
    float wa = an.w - an.y;
    float w = expf(rg.w) * wa;
    float h = expf(rg.z) * ha;
    float yc = rg.x * ha + yca;
    float xc = rg.y * wa + xca;
    x1 = fmaxf(xc - w * 0.5f, 0.0f) / CROPF;
    y1 = fmaxf(yc - h * 0.5f, 0.0f) / CROPF;
    x2 = fminf(xc + w * 0.5f, CROPF - 1.0f) / CROPF;
    y2 = fminf(yc + h * 0.5f, CROPF - 1.0f) / CROPF;
}

// Phase 1: conf -> (scores, cls) only. LDS-staged coalesced float4 reads,
// 4 lanes per anchor for the class argmax (identical tie-break to validated r2).
// NO global atomics, no box decode here.
__global__ __launch_bounds__(256) void phase1_kernel(
    const float* __restrict__ conf, float* __restrict__ scores,
    unsigned char* __restrict__ cls)
{
    __shared__ float lds[CHUNK];
    const int blk = blockIdx.x, t = threadIdx.x;
    const float4* src = reinterpret_cast<const float4*>(conf + (size_t)blk * CHUNK);
    float4* dst = reinterpret_cast<float4*>(lds);
    for (int i = t; i < CHUNK / 4; i += 256) dst[i] = src[i];
    __syncthreads();

    const int la = t >> 2, sub = t & 3;
    const int quad = blk * APB + la;           // global anchor b*NA + a
    const float* crow = lds + la * 81;
    float best = -3.0e38f; int bc = 255;
    for (int c = sub; c <= NCLS; c += 4) {
        if (c == 0) continue;                  // background stripped
        float v = crow[c];
        if (v > best) { best = v; bc = c; }    // strict > : first-index tie-break
    }
    for (int m = 1; m <= 2; m <<= 1) {
        float ov = __shfl_xor(best, m);
        int oc = __shfl_xor(bc, m);
        if (ov > best || (ov == best && oc < bc)) { best = ov; bc = oc; }
    }
    if (sub == 0) {
        scores[quad] = 1.0f / (1.0f + expf(-best));
        cls[quad] = (unsigned char)(bc - 1);
    }
}

// block-wide inclusive SUFFIX scan over 1024 values; result into outarr[t].
__device__ __forceinline__ void suffix_scan_1024(uint32_t v, int t,
                                                 uint32_t* wtot, uint32_t* outarr) {
    uint32_t r = v;
    const int lane = t & 63, w = t >> 6;
    #pragma unroll
    for (int m = 1; m < 64; m <<= 1) {
        uint32_t o = __shfl_down(r, m);
        if (lane + m < 64) r += o;
    }
    if (lane == 0) wtot[w] = r;
    __syncthreads();
    if (t < 16) {
        uint32_t v0 = wtot[t], x = v0;
        #pragma unroll
        for (int m = 1; m < 16; m <<= 1) {
            uint32_t o = __shfl_down(x, m);
            if (t + m < 16) x += o;
        }
        wtot[t] = x - v0;                      // exclusive suffix of wave totals
    }
    __syncthreads();
    outarr[t] = r + wtot[w];
    __syncthreads();
}

// Phase 2: one block/image. Pass A: fused bmax(decode all boxes) + coarse hist.
// Radix-select top >=NSEL, bitonic sort, 512x512 suppression-mask,
// wave-parallel ffs greedy scan (exact), serial fallback past 512.
__global__ __launch_bounds__(1024) void phase2_kernel(
    const float* __restrict__ reg, const float* __restrict__ anch,
    const float* __restrict__ scores, const unsigned char* __restrict__ cls,
    float* __restrict__ out)
{
    __shared__ uint64_t s_mask[4096];      // 32KB  alias: hist u32[8192]
    __shared__ float4   s_boxo[512];       // 8KB   alias: fhist u32[2048]
    __shared__ uint64_t s_keys[MKEYS];     // 16KB  alias: csum u32[1024] (first 4KB)
    __shared__ float4   s_keptbox[TOPK];   // 3.2KB (fallback only)
    __shared__ float    s_areao[512];      // 2KB
    __shared__ uint32_t s_ccount[NCLS];
    __shared__ uint32_t s_kinfo[TOPK];
    __shared__ uint32_t s_wtot[16];
    __shared__ uint32_t s_shv[8];
    __shared__ float    s_bmaxarr[16];
    __shared__ float    s_offm;
    __shared__ uint8_t  s_clsl[512];

    uint32_t* hist  = (uint32_t*)s_mask;
    uint32_t* fhist = (uint32_t*)s_boxo;
    uint32_t* csum  = (uint32_t*)s_keys;

    const int b = blockIdx.x;
    const int t = threadIdx.x;
    const float* sc = scores + (size_t)b * NA;

    // ---- init
    for (int i = t; i < 8192; i += 1024) hist[i] = 0;
    if (t < NCLS) s_ccount[t] = 0;
    if (t < 8) s_shv[t] = 0;
    __syncthreads();

    // ---- Pass A: coarse histogram (bits>>17) + per-image box-coordinate max
    float bmaxl = 0.0f;   // decoded x1,y1 >= 0 so 0 is a safe identity
    for (int g = t; g < NA; g += 1024) {
        float s = sc[g];
        if (s > CONF_T) atomicAdd(&hist[__float_as_uint(s) >> 17], 1u);
        float4 rg = reinterpret_cast<const float4*>(reg)[(size_t)b * NA + g];
        float4 an = reinterpret_cast<const float4*>(anch)[g];
        float x1, y1, x2, y2; decode_box(rg, an, x1, y1, x2, y2);
        bmaxl = fmaxf(bmaxl, fmaxf(fmaxf(x1, y1), fmaxf(x2, y2)));
    }
    #pragma unroll
    for (int m = 1; m < 64; m <<= 1) bmaxl = fmaxf(bmaxl, __shfl_xor(bmaxl, m));
    if ((t & 63) == 0) s_bmaxarr[t >> 6] = bmaxl;
    __syncthreads();

    // ---- coarse crossing via parallel suffix scan over 1024 chunk-sums
    uint32_t v8 = 0;
    #pragma unroll
    for (int k = 0; k < 8; ++k) v8 += hist[t * 8 + k];
    suffix_scan_1024(v8, t, s_wtot, csum);
    {
        uint32_t sIn = csum[t];
        uint32_t sNext = (t == 1023) ? 0u : csum[t + 1];
        if (sIn >= NSEL && sNext < NSEL) { s_shv[0] = (uint32_t)t; s_shv[1] = sNext; s_shv[2] = 1; }
    }
    __syncthreads();
    // zero fhist; t0 resolves coarse bin within the chunk; also finalize offm
    for (int i = t; i < 2048; i += 1024) fhist[i] = 0;
    if (t == 0) {
        float mx = s_bmaxarr[0];
        #pragma unroll
        for (int k = 1; k < 16; ++k) mx = fmaxf(mx, s_bmaxarr[k]);
        s_offm = mx + 1.0f;                    // jnp.max(boxes) + 1
        if (s_shv[2]) {
            uint32_t chunk = s_shv[0], run2 = s_shv[1]; int cb = -1; uint32_t ab = 0;
            for (int k = 7; k >= 0; --k) {
                uint32_t v = hist[chunk * 8 + k];
                if (cb < 0 && run2 + v >= NSEL) { cb = (int)(chunk * 8 + k); ab = run2; }
                run2 += v;
            }
            s_shv[0] = (uint32_t)cb; s_shv[1] = ab;
        }
    }
    __syncthreads();

    const uint32_t found = s_shv[2], cbin = s_shv[0], above = s_shv[1];
    // ---- fine histogram ((bits>>6)&2047 within coarse bin)
    if (found) {
        for (int g = t; g < NA; g += 1024) {
            float s = sc[g];
            if (s > CONF_T) {
                uint32_t bits = __float_as_uint(s);
                if ((bits >> 17) == cbin) atomicAdd(&fhist[(bits >> 6) & 2047u], 1u);
            }
        }
    }
    __syncthreads();
    uint32_t fv = fhist[2 * t] + fhist[2 * t + 1];
    suffix_scan_1024(fv, t, s_wtot, csum);
    if (found) {
        uint32_t sIn = csum[t] + above;
        uint32_t sNext = ((t == 1023) ? 0u : csum[t + 1]) + above;
        if (sIn >= NSEL && sNext < NSEL) { s_shv[5] = (uint32_t)t; s_shv[6] = sNext; }
    }
    __syncthreads();
    if (t == 0) {
        if (found) {
            uint32_t pc = s_shv[5], ab2 = s_shv[6];
            uint32_t v1 = fhist[pc * 2 + 1];
            uint32_t fbin = (ab2 + v1 >= NSEL) ? (pc * 2 + 1) : (pc * 2);
            s_shv[3] = (cbin << 11) | fbin;
        } else s_shv[3] = 0;
    }
    __syncthreads();

    // ---- gather candidates (score bits >> 6) >= T   (csum dead; zero keys)
    const uint32_t T = s_shv[3];
    for (int i = t; i < MKEYS; i += 1024) s_keys[i] = 0ull;
    __syncthreads();
    for (int g = t; g < NA; g += 1024) {
        float s = sc[g];
        if (s > CONF_T) {
            uint32_t bits = __float_as_uint(s);
            if ((bits >> 6) >= T) {
                uint32_t pos = atomicAdd(&s_shv[4], 1u);
                if (pos < MKEYS)
                    s_keys[pos] = ((uint64_t)bits << 32) |
                                  (uint64_t)(0xFFFFFFFFu - (uint32_t)g);
            }
        }
    }
    __syncthreads();

    uint32_t nG = s_shv[4]; if (nG > MKEYS) nG = MKEYS;
    uint32_t SS = 512; while (SS < nG) SS <<= 1;

    // ---- bitonic sort descending over SS (padding zeros sink)
    for (uint32_t k = 2; k <= SS; k <<= 1) {
        for (uint32_t j = k >> 1; j > 0; j >>= 1) {
            for (uint32_t i = t; i < SS; i += 1024) {
                uint32_t ixj = i ^ j;
                if (ixj > i) {
                    uint64_t a = s_keys[i], bb2 = s_keys[ixj];
                    bool sw = ((i & k) == 0) ? (a < bb2) : (a > bb2);
                    if (sw) { s_keys[i] = bb2; s_keys[ixj] = a; }
                }
            }
            __syncthreads();
        }
    }

    // ---- prep first 512: offset boxes, areas, classes  (fhist dead)
    const float offm = s_offm;
    if (t < 512) {
        if ((uint32_t)t < nG) {
            uint64_t key = s_keys[t];
            uint32_t g = 0xFFFFFFFFu - (uint32_t)key;
            size_t qi = (size_t)b * NA + g;
            int c = (int)cls[qi];
            s_clsl[t] = (uint8_t)c;
            float4 rg = reinterpret_cast<const float4*>(reg)[qi];
            float4 an = reinterpret_cast<const float4*>(anch)[g];
            float x1, y1, x2, y2; decode_box(rg, an, x1, y1, x2, y2);
            float off = (float)c * offm;
            float4 bo = make_float4(x1 + off, y1 + off, x2 + off, y2 + off);
            s_boxo[t] = bo;
            s_areao[t] = (bo.z - bo.x) * (bo.w - bo.y);
        } else {
            s_clsl[t] = 0;
            s_boxo[t] = make_float4(0.f, 0.f, 0.f, 0.f);
            s_areao[t] = 0.f;
        }
    }
    __syncthreads();

    // ---- suppression mask: mask[w*512+i] = cols [64w,64w+64) of row i  (hist dead)
    {
        const int i = t & 511;
        const float4 bi = s_boxo[i];
        const float aI = s_areao[i];
        for (int w = (t >> 9); w < 8; w += 2) {
            uint64_t m = 0ull;
            for (int jj = 0; jj < 64; ++jj) {
                float4 bj = s_boxo[w * 64 + jj];       // wave-broadcast read
                float ix1 = fmaxf(bi.x, bj.x), iy1 = fmaxf(bi.y, bj.y);
                float ix2 = fminf(bi.z, bj.z), iy2 = fminf(bi.w, bj.w);
                float inter = fmaxf(ix2 - ix1, 0.f) * fmaxf(iy2 - iy1, 0.f);
                float uni = aI + s_areao[w * 64 + jj] - inter;
                if (uni > 0.f && inter + inter > uni) m |= (1ull << jj);
            }
            s_mask[(size_t)w * 512 + i] = m;
        }
    }
    __syncthreads();

    // ---- wave-parallel exact greedy scan (wave 0): ffs + parallel mask ANDs
    if (t < 64) {
        const int lane = t;
        const int lim = (nG < 512u) ? (int)nG : 512;
        uint64_t alive = 0ull;
        if (lane < 8) {
            int lo = lane * 64, n = lim - lo;
            if (n >= 64) alive = ~0ull;
            else if (n > 0) alive = (~0ull) >> (64 - n);
        }
        int nk = 0;
        while (nk < TOPK) {
            uint32_t cand = 0xFFFFFFFFu;
            if (alive) cand = (uint32_t)(lane * 64) + (uint32_t)__builtin_ctzll(alive);
            #pragma unroll
            for (int m = 1; m <= 4; m <<= 1) cand = min(cand, __shfl_xor(cand, m));
            if (cand == 0xFFFFFFFFu) break;
            const int i = (int)cand;
            if (lane == 0) {
                int c = (int)s_clsl[i];
                uint32_t slot = s_ccount[c]; s_ccount[c] = slot + 1;
                s_kinfo[nk] = (uint32_t)i | (slot << 11) | ((uint32_t)c << 19);
            }
            ++nk;
            if (lane < 8) {
                alive &= ~s_mask[(size_t)lane * 512 + i];
                if ((i >> 6) == lane) alive &= ~(1ull << (i & 63));
            }
        }
        // fallback past 512 (exactness insurance; ~never taken)
        if (lane == 0) {
            if (nk < TOPK && nG > 512u) {
                for (int k2 = 0; k2 < nk; ++k2)
                    s_keptbox[k2] = s_boxo[s_kinfo[k2] & 2047u];
                for (uint32_t ci = 512; ci < nG && nk < TOPK; ++ci) {
                    uint64_t key = s_keys[ci];
                    uint32_t g = 0xFFFFFFFFu - (uint32_t)key;
                    size_t qi = (size_t)b * NA + g;
                    int c = (int)cls[qi];
                    float4 rg = reinterpret_cast<const float4*>(reg)[qi];
                    float4 an = reinterpret_cast<const float4*>(anch)[g];
                    float x1, y1, x2, y2; decode_box(rg, an, x1, y1, x2, y2);
                    float off = (float)c * offm;
                    float4 bo = make_float4(x1 + off, y1 + off, x2 + off, y2 + off);
                    float aB2 = (bo.z - bo.x) * (bo.w - bo.y);
                    bool sup = false;
                    for (int k2 = 0; k2 < nk && !sup; ++k2) {
                        float4 kb = s_keptbox[k2];
                        float aK = (kb.z - kb.x) * (kb.w - kb.y);
                        float ix1 = fmaxf(bo.x, kb.x), iy1 = fmaxf(bo.y, kb.y);
                        float ix2 = fminf(bo.z, kb.z), iy2 = fminf(bo.w, kb.w);
                        float inter = fmaxf(ix2 - ix1, 0.f) * fmaxf(iy2 - iy1, 0.f);
                        float uni = aB2 + aK - inter;
                        sup = (uni > 0.f && inter + inter > uni);
                    }
                    if (!sup) {
                        uint32_t slot = s_ccount[c]; s_ccount[c] = slot + 1;
                        s_kinfo[nk] = ci | (slot << 11) | ((uint32_t)c << 19);
                        s_keptbox[nk] = bo;
                        ++nk;
                    }
                }
            }
            s_shv[7] = (uint32_t)nk;
        }
    }
    __syncthreads();

    // ---- parallel output
    uint32_t nk = s_shv[7];
    if ((uint32_t)t < nk) {
        uint32_t info = s_kinfo[t];
        uint32_t i = info & 2047u;
        uint32_t slot = (info >> 11) & 255u;
        uint32_t c = (info >> 19) & 127u;
        uint64_t key = s_keys[i];
        uint32_t g = 0xFFFFFFFFu - (uint32_t)key;
        float scv = __uint_as_float((uint32_t)(key >> 32));
        size_t qi = (size_t)b * NA + g;
        float4 rg = reinterpret_cast<const float4*>(reg)[qi];
        float4 an = reinterpret_cast<const float4*>(anch)[g];
        float x1, y1, x2, y2; decode_box(rg, an, x1, y1, x2, y2);
        float* o = out + (((size_t)b * (NCLS + 1) + (size_t)(c + 1)) * TOPK + slot) * 5;
        o[0] = scv; o[1] = x1; o[2] = y1; o[3] = x2; o[4] = y2;
    }
}

extern "C" void kernel_launch(void* const* d_in, const int* in_sizes, int n_in,
                              void* d_out, int out_size, void* d_ws, size_t ws_size,
                              hipStream_t stream)
{
    const float* conf = (const float*)d_in[0];   // [B, A, 81] f32
    const float* reg  = (const float*)d_in[1];   // [B, A, 4]  f32
    const float* anch = (const float*)d_in[2];   // [A, 4]     f32
    float* out = (float*)d_out;                  // [B, 81, 200, 5] f32

    char* ws = (char*)d_ws;
    float* scores = (float*)ws;                                  // NB*NA f32
    unsigned char* cls = (unsigned char*)(ws + (size_t)NB * NA * 4);  // NB*NA u8

    hipMemsetAsync(d_out, 0, (size_t)out_size * sizeof(float), stream);

    int blocks = (NB * NA) / APB;        // 6138 exact
    phase1_kernel<<<blocks, 256, 0, stream>>>(conf, scores, cls);
    phase2_kernel<<<NB, 1024, 0, stream>>>(reg, anch, scores, cls, out);
}

// Round 4
// 176.087 us; speedup vs baseline: 3.2080x; 1.2246x over previous
//
#include <hip/hip_runtime.h>
#include <stdint.h>

#define NCLS 80
#define TOPK 200
#define CONF_T 0.05f
#define CROPF 300.0f
#define NA 49104
#define NA4 (NA / 4)
#define NB 8
#define NSEL 512
#define MKEYS 2048
#define APB 64
#define CHUNK (APB * 81)
#define NGRP (NA / 16)          // 3069 16-anchor groups per image (16 | NA)
#define MROW 9                  // mask row stride in u64 (padded: conflict-free reads)

__device__ __forceinline__ void decode_box(const float4 rg, const float4 an,
                                           float& x1, float& y1, float& x2, float& y2) {
    // anchors: (ymin, xmin, ymax, xmax); reg: (dy, dx, dh, dw)
    float yca = (an.x + an.z) * 0.5f;
    float xca = (an.y + an.w) * 0.5f;
    float ha = an.z - an.x;
    float wa = an.w - an.y;
    float w = expf(rg.w) * wa;
    float h = expf(rg.z) * ha;
    float yc = rg.x * ha + yca;
    float xc = rg.y * wa + xca;
    x1 = fmaxf(xc - w * 0.5f, 0.0f) / CROPF;
    y1 = fmaxf(yc - h * 0.5f, 0.0f) / CROPF;
    x2 = fminf(xc + w * 0.5f, CROPF - 1.0f) / CROPF;
    y2 = fminf(yc + h * 0.5f, CROPF - 1.0f) / CROPF;
}

// Phase 1: conf -> (scores, cls); reg+anch -> per-16-anchor-group box-coord max
// (groupmax, no atomics; groups never straddle images since 16 | NA).
__global__ __launch_bounds__(256) void phase1_kernel(
    const float* __restrict__ conf, const float* __restrict__ reg,
    const float* __restrict__ anch, float* __restrict__ scores,
    unsigned char* __restrict__ cls, float* __restrict__ groupmax)
{
    __shared__ float lds[CHUNK];
    const int blk = blockIdx.x, t = threadIdx.x;
    const float4* src = reinterpret_cast<const float4*>(conf + (size_t)blk * CHUNK);
    float4* dst = reinterpret_cast<float4*>(lds);
    for (int i = t; i < CHUNK / 4; i += 256) dst[i] = src[i];
    __syncthreads();

    const int la = t >> 2, sub = t & 3;
    const int quad = blk * APB + la;           // global anchor b*NA + a
    const float* crow = lds + la * 81;
    float best = -3.0e38f; int bc = 255;
    for (int c = sub; c <= NCLS; c += 4) {
        if (c == 0) continue;                  // background stripped
        float v = crow[c];
        if (v > best) { best = v; bc = c; }    // strict > : first-index tie-break
    }
    for (int m = 1; m <= 2; m <<= 1) {
        float ov = __shfl_xor(best, m);
        int oc = __shfl_xor(bc, m);
        if (ov > best || (ov == best && oc < bc)) { best = ov; bc = oc; }
    }
    float bmaxl = 0.0f;                        // decoded coords: y1 >= 0 so 0 is safe identity
    if (sub == 0) {
        scores[quad] = 1.0f / (1.0f + expf(-best));
        cls[quad] = (unsigned char)(bc - 1);
        int a = quad % NA;
        float4 rg = reinterpret_cast<const float4*>(reg)[quad];
        float4 an = reinterpret_cast<const float4*>(anch)[a];
        float x1, y1, x2, y2; decode_box(rg, an, x1, y1, x2, y2);
        bmaxl = fmaxf(fmaxf(x1, y1), fmaxf(x2, y2));
    }
    #pragma unroll
    for (int m = 1; m < 64; m <<= 1) bmaxl = fmaxf(bmaxl, __shfl_xor(bmaxl, m));
    if ((t & 63) == 0) groupmax[blk * 4 + (t >> 6)] = bmaxl;  // group = global quad/16
}

// block-wide inclusive SUFFIX scan over 1024 values; result into outarr[t].
__device__ __forceinline__ void suffix_scan_1024(uint32_t v, int t,
                                                 uint32_t* wtot, uint32_t* outarr) {
    uint32_t r = v;
    const int lane = t & 63, w = t >> 6;
    #pragma unroll
    for (int m = 1; m < 64; m <<= 1) {
        uint32_t o = __shfl_down(r, m);
        if (lane + m < 64) r += o;
    }
    if (lane == 0) wtot[w] = r;
    __syncthreads();
    if (t < 16) {
        uint32_t v0 = wtot[t], x = v0;
        #pragma unroll
        for (int m = 1; m < 16; m <<= 1) {
            uint32_t o = __shfl_down(x, m);
            if (t + m < 16) x += o;
        }
        wtot[t] = x - v0;                      // exclusive suffix of wave totals
    }
    __syncthreads();
    outarr[t] = r + wtot[w];
    __syncthreads();
}

// Phase 2: one block/image. float4 score passes; radix-select top >=NSEL;
// bitonic sort; padded 512x512 suppression mask; wave-parallel ffs greedy scan.
__global__ __launch_bounds__(1024) void phase2_kernel(
    const float* __restrict__ reg, const float* __restrict__ anch,
    const float* __restrict__ scores, const unsigned char* __restrict__ cls,
    const float* __restrict__ groupmax, float* __restrict__ out)
{
    __shared__ uint64_t s_mask[512 * MROW];// 36.9KB  alias: hist u32[8192]
    __shared__ float4   s_boxo[512];       // 8KB     alias: fhist u32[2048]
    __shared__ uint64_t s_keys[MKEYS];     // 16KB    alias: csum u32[1024] (first 4KB)
    __shared__ float4   s_keptbox[TOPK];   // 3.2KB (fallback only)
    __shared__ float    s_areao[512];      // 2KB
    __shared__ uint32_t s_ccount[NCLS];
    __shared__ uint32_t s_kinfo[TOPK];
    __shared__ uint32_t s_wtot[16];
    __shared__ uint32_t s_shv[8];
    __shared__ float    s_bmaxarr[16];
    __shared__ float    s_offm;
    __shared__ uint8_t  s_clsl[512];

    uint32_t* hist  = (uint32_t*)s_mask;
    uint32_t* fhist = (uint32_t*)s_boxo;
    uint32_t* csum  = (uint32_t*)s_keys;

    const int b = blockIdx.x;
    const int t = threadIdx.x;
    const float* sc = scores + (size_t)b * NA;
    const float4* sc4 = reinterpret_cast<const float4*>(sc);

    // ---- init
    for (int i = t; i < 8192; i += 1024) hist[i] = 0;
    if (t < NCLS) s_ccount[t] = 0;
    if (t < 8) s_shv[t] = 0;
    __syncthreads();

    // ---- per-image box max from precomputed group maxes (12KB)
    {
        const float* gm = groupmax + (size_t)b * NGRP;
        float wm = 0.0f;
        for (int i = t; i < NGRP; i += 1024) wm = fmaxf(wm, gm[i]);
        #pragma unroll
        for (int m = 1; m < 64; m <<= 1) wm = fmaxf(wm, __shfl_xor(wm, m));
        if ((t & 63) == 0) s_bmaxarr[t >> 6] = wm;
    }

    // ---- Pass A: coarse histogram (bits>>17), float4
    #define HIST1(s) { if ((s) > CONF_T) atomicAdd(&hist[__float_as_uint(s) >> 17], 1u); }
    for (int i = t; i < NA4; i += 1024) {
        float4 s4 = sc4[i];
        HIST1(s4.x) HIST1(s4.y) HIST1(s4.z) HIST1(s4.w)
    }
    __syncthreads();

    // ---- coarse crossing via parallel suffix scan over 1024 chunk-sums
    uint32_t v8 = 0;
    #pragma unroll
    for (int k = 0; k < 8; ++k) v8 += hist[t * 8 + k];
    suffix_scan_1024(v8, t, s_wtot, csum);
    {
        uint32_t sIn = csum[t];
        uint32_t sNext = (t == 1023) ? 0u : csum[t + 1];
        if (sIn >= NSEL && sNext < NSEL) { s_shv[0] = (uint32_t)t; s_shv[1] = sNext; s_shv[2] = 1; }
    }
    __syncthreads();
    // zero fhist; t0 resolves coarse bin within the chunk; finalize offm
    for (int i = t; i < 2048; i += 1024) fhist[i] = 0;
    if (t == 0) {
        float mx = s_bmaxarr[0];
        #pragma unroll
        for (int k = 1; k < 16; ++k) mx = fmaxf(mx, s_bmaxarr[k]);
        s_offm = mx + 1.0f;                    // jnp.max(boxes) + 1
        if (s_shv[2]) {
            uint32_t chunk = s_shv[0], run2 = s_shv[1]; int cb = -1; uint32_t ab = 0;
            for (int k = 7; k >= 0; --k) {
                uint32_t v = hist[chunk * 8 + k];
                if (cb < 0 && run2 + v >= NSEL) { cb = (int)(chunk * 8 + k); ab = run2; }
                run2 += v;
            }
            s_shv[0] = (uint32_t)cb; s_shv[1] = ab;
        }
    }
    __syncthreads();

    const uint32_t found = s_shv[2], cbin = s_shv[0], above = s_shv[1];
    // ---- fine histogram ((bits>>6)&2047 within coarse bin), float4
    #define FHIST1(s) { if ((s) > CONF_T) { uint32_t _b = __float_as_uint(s); \
        if ((_b >> 17) == cbin) atomicAdd(&fhist[(_b >> 6) & 2047u], 1u); } }
    if (found) {
        for (int i = t; i < NA4; i += 1024) {
            float4 s4 = sc4[i];
            FHIST1(s4.x) FHIST1(s4.y) FHIST1(s4.z) FHIST1(s4.w)
        }
    }
    __syncthreads();
    uint32_t fv = fhist[2 * t] + fhist[2 * t + 1];
    suffix_scan_1024(fv, t, s_wtot, csum);
    if (found) {
        uint32_t sIn = csum[t] + above;
        uint32_t sNext = ((t == 1023) ? 0u : csum[t + 1]) + above;
        if (sIn >= NSEL && sNext < NSEL) { s_shv[5] = (uint32_t)t; s_shv[6] = sNext; }
    }
    __syncthreads();
    if (t == 0) {
        if (found) {
            uint32_t pc = s_shv[5], ab2 = s_shv[6];
            uint32_t v1 = fhist[pc * 2 + 1];
            uint32_t fbin = (ab2 + v1 >= NSEL) ? (pc * 2 + 1) : (pc * 2);
            s_shv[3] = (cbin << 11) | fbin;
        } else s_shv[3] = 0;
    }
    __syncthreads();

    // ---- gather candidates (score bits >> 6) >= T   (csum dead; zero keys)
    const uint32_t T = s_shv[3];
    for (int i = t; i < MKEYS; i += 1024) s_keys[i] = 0ull;
    __syncthreads();
    #define GATH1(s, g) { if ((s) > CONF_T) { uint32_t _b = __float_as_uint(s); \
        if ((_b >> 6) >= T) { uint32_t _p = atomicAdd(&s_shv[4], 1u); \
            if (_p < MKEYS) s_keys[_p] = ((uint64_t)_b << 32) | \
                (uint64_t)(0xFFFFFFFFu - (uint32_t)(g)); } } }
    for (int i = t; i < NA4; i += 1024) {
        float4 s4 = sc4[i];
        GATH1(s4.x, 4 * i)     GATH1(s4.y, 4 * i + 1)
        GATH1(s4.z, 4 * i + 2) GATH1(s4.w, 4 * i + 3)
    }
    __syncthreads();

    uint32_t nG = s_shv[4]; if (nG > MKEYS) nG = MKEYS;
    uint32_t SS = 512; while (SS < nG) SS <<= 1;

    // ---- bitonic sort descending over SS (padding zeros sink)
    for (uint32_t k = 2; k <= SS; k <<= 1) {
        for (uint32_t j = k >> 1; j > 0; j >>= 1) {
            for (uint32_t i = t; i < SS; i += 1024) {
                uint32_t ixj = i ^ j;
                if (ixj > i) {
                    uint64_t a = s_keys[i], bb2 = s_keys[ixj];
                    bool sw = ((i & k) == 0) ? (a < bb2) : (a > bb2);
                    if (sw) { s_keys[i] = bb2; s_keys[ixj] = a; }
                }
            }
            __syncthreads();
        }
    }

    // ---- prep first 512: offset boxes, areas, classes  (fhist dead)
    const float offm = s_offm;
    if (t < 512) {
        if ((uint32_t)t < nG) {
            uint64_t key = s_keys[t];
            uint32_t g = 0xFFFFFFFFu - (uint32_t)key;
            size_t qi = (size_t)b * NA + g;
            int c = (int)cls[qi];
            s_clsl[t] = (uint8_t)c;
            float4 rg = reinterpret_cast<const float4*>(reg)[qi];
            float4 an = reinterpret_cast<const float4*>(anch)[g];
            float x1, y1, x2, y2; decode_box(rg, an, x1, y1, x2, y2);
            float off = (float)c * offm;
            float4 bo = make_float4(x1 + off, y1 + off, x2 + off, y2 + off);
            s_boxo[t] = bo;
            s_areao[t] = (bo.z - bo.x) * (bo.w - bo.y);
        } else {
            s_clsl[t] = 0;
            s_boxo[t] = make_float4(0.f, 0.f, 0.f, 0.f);
            s_areao[t] = 0.f;
        }
    }
    __syncthreads();

    // ---- suppression mask: s_mask[i*MROW + w] = cols [64w,64w+64) of row i
    {
        const int i = t & 511;
        const float4 bi = s_boxo[i];
        const float aI = s_areao[i];
        for (int w = (t >> 9); w < 8; w += 2) {
            uint64_t m = 0ull;
            for (int jj = 0; jj < 64; ++jj) {
                float4 bj = s_boxo[w * 64 + jj];       // wave-broadcast read
                float ix1 = fmaxf(bi.x, bj.x), iy1 = fmaxf(bi.y, bj.y);
                float ix2 = fminf(bi.z, bj.z), iy2 = fminf(bi.w, bj.w);
                float inter = fmaxf(ix2 - ix1, 0.f) * fmaxf(iy2 - iy1, 0.f);
                float uni = aI + s_areao[w * 64 + jj] - inter;
                if (uni > 0.f && inter + inter > uni) m |= (1ull << jj);
            }
            s_mask[(size_t)i * MROW + w] = m;
        }
    }
    __syncthreads();

    // ---- wave-parallel exact greedy scan (wave 0): ffs + parallel mask ANDs
    if (t < 64) {
        const int lane = t;
        const int lim = (nG < 512u) ? (int)nG : 512;
        uint64_t alive = 0ull;
        if (lane < 8) {
            int lo = lane * 64, n = lim - lo;
            if (n >= 64) alive = ~0ull;
            else if (n > 0) alive = (~0ull) >> (64 - n);
        }
        int nk = 0;
        while (nk < TOPK) {
            uint32_t cand = 0xFFFFFFFFu;
            if (alive) cand = (uint32_t)(lane * 64) + (uint32_t)__builtin_ctzll(alive);
            #pragma unroll
            for (int m = 1; m <= 4; m <<= 1) cand = min(cand, __shfl_xor(cand, m));
            if (cand == 0xFFFFFFFFu) break;
            const int i = (int)cand;
            if (lane == 0) {
                int c = (int)s_clsl[i];
                uint32_t slot = s_ccount[c]; s_ccount[c] = slot + 1;
                s_kinfo[nk] = (uint32_t)i | (slot << 11) | ((uint32_t)c << 19);
            }
            ++nk;
            if (lane < 8) {
                alive &= ~s_mask[(size_t)i * MROW + lane];
                if ((i >> 6) == lane) alive &= ~(1ull << (i & 63));
            }
        }
        // fallback past 512 (exactness insurance; ~never taken)
        if (lane == 0) {
            if (nk < TOPK && nG > 512u) {
                for (int k2 = 0; k2 < nk; ++k2)
                    s_keptbox[k2] = s_boxo[s_kinfo[k2] & 2047u];
                for (uint32_t ci = 512; ci < nG && nk < TOPK; ++ci) {
                    uint64_t key = s_keys[ci];
                    uint32_t g = 0xFFFFFFFFu - (uint32_t)key;
                    size_t qi = (size_t)b * NA + g;
                    int c = (int)cls[qi];
                    float4 rg = reinterpret_cast<const float4*>(reg)[qi];
                    float4 an = reinterpret_cast<const float4*>(anch)[g];
                    float x1, y1, x2, y2; decode_box(rg, an, x1, y1, x2, y2);
                    float off = (float)c * offm;
                    float4 bo = make_float4(x1 + off, y1 + off, x2 + off, y2 + off);
                    float aB2 = (bo.z - bo.x) * (bo.w - bo.y);
                    bool sup = false;
                    for (int k2 = 0; k2 < nk && !sup; ++k2) {
                        float4 kb = s_keptbox[k2];
                        float aK = (kb.z - kb.x) * (kb.w - kb.y);
                        float ix1 = fmaxf(bo.x, kb.x), iy1 = fmaxf(bo.y, kb.y);
                        float ix2 = fminf(bo.z, kb.z), iy2 = fminf(bo.w, kb.w);
                        float inter = fmaxf(ix2 - ix1, 0.f) * fmaxf(iy2 - iy1, 0.f);
                        float uni = aB2 + aK - inter;
                        sup = (uni > 0.f && inter + inter > uni);
                    }
                    if (!sup) {
                        uint32_t slot = s_ccount[c]; s_ccount[c] = slot + 1;
                        s_kinfo[nk] = ci | (slot << 11) | ((uint32_t)c << 19);
                        s_keptbox[nk] = bo;
                        ++nk;
                    }
                }
            }
            s_shv[7] = (uint32_t)nk;
        }
    }
    __syncthreads();

    // ---- parallel output
    uint32_t nk = s_shv[7];
    if ((uint32_t)t < nk) {
        uint32_t info = s_kinfo[t];
        uint32_t i = info & 2047u;
        uint32_t slot = (info >> 11) & 255u;
        uint32_t c = (info >> 19) & 127u;
        uint64_t key = s_keys[i];
        uint32_t g = 0xFFFFFFFFu - (uint32_t)key;
        float scv = __uint_as_float((uint32_t)(key >> 32));
        size_t qi = (size_t)b * NA + g;
        float4 rg = reinterpret_cast<const float4*>(reg)[qi];
        float4 an = reinterpret_cast<const float4*>(anch)[g];
        float x1, y1, x2, y2; decode_box(rg, an, x1, y1, x2, y2);
        float* o = out + (((size_t)b * (NCLS + 1) + (size_t)(c + 1)) * TOPK + slot) * 5;
        o[0] = scv; o[1] = x1; o[2] = y1; o[3] = x2; o[4] = y2;
    }
}

extern "C" void kernel_launch(void* const* d_in, const int* in_sizes, int n_in,
                              void* d_out, int out_size, void* d_ws, size_t ws_size,
                              hipStream_t stream)
{
    const float* conf = (const float*)d_in[0];   // [B, A, 81] f32
    const float* reg  = (const float*)d_in[1];   // [B, A, 4]  f32
    const float* anch = (const float*)d_in[2];   // [A, 4]     f32
    float* out = (float*)d_out;                  // [B, 81, 200, 5] f32

    char* ws = (char*)d_ws;
    float* scores = (float*)ws;                                       // NB*NA f32
    unsigned char* cls = (unsigned char*)(ws + (size_t)NB * NA * 4);  // NB*NA u8
    float* groupmax = (float*)(ws + (size_t)NB * NA * 5);             // NB*NGRP f32

    hipMemsetAsync(d_out, 0, (size_t)out_size * sizeof(float), stream);

    int blocks = (NB * NA) / APB;        // 6138 exact
    phase1_kernel<<<blocks, 256, 0, stream>>>(conf, reg, anch, scores, cls, groupmax);
    phase2_kernel<<<NB, 1024, 0, stream>>>(reg, anch, scores, cls, groupmax, out);
}

// Round 5
// 118.138 us; speedup vs baseline: 4.7816x; 1.4905x over previous
//
#include <hip/hip_runtime.h>
#include <stdint.h>

#define NCLS 80
#define TOPK 200
#define CONF_T 0.05f
#define CROPF 300.0f
#define NA 49104
#define NA4 (NA / 4)
#define NB 8
#define NSEL 512
#define MKEYS 2048
#define APB 64
#define CHUNK (APB * 81)
#define NGRP (NA / 16)          // 3069 16-anchor groups per image (16 | NA)
#define MROW 9                  // mask row stride in u64 (padded)

__device__ __forceinline__ void decode_box(const float4 rg, const float4 an,
                                           float& x1, float& y1, float& x2, float& y2) {
    // anchors: (ymin, xmin, ymax, xmax); reg: (dy, dx, dh, dw)
    float yca = (an.x + an.z) * 0.5f;
    float xca = (an.y + an.w) * 0.5f;
    float ha = an.z - an.x;
    float wa = an.w - an.y;
    float w = expf(rg.w) * wa;
    float h = expf(rg.z) * ha;
    float yc = rg.x * ha + yca;
    float xc = rg.y * wa + xca;
    x1 = fmaxf(xc - w * 0.5f, 0.0f) / CROPF;
    y1 = fmaxf(yc - h * 0.5f, 0.0f) / CROPF;
    x2 = fminf(xc + w * 0.5f, CROPF - 1.0f) / CROPF;
    y2 = fminf(yc + h * 0.5f, CROPF - 1.0f) / CROPF;
}

// Phase 1 (unchanged from validated r4): conf -> (scores, cls); per-16-anchor
// groupmax of decoded box coords (no atomics; 16 | NA so groups never straddle images).
__global__ __launch_bounds__(256) void phase1_kernel(
    const float* __restrict__ conf, const float* __restrict__ reg,
    const float* __restrict__ anch, float* __restrict__ scores,
    unsigned char* __restrict__ cls, float* __restrict__ groupmax)
{
    __shared__ float lds[CHUNK];
    const int blk = blockIdx.x, t = threadIdx.x;
    const float4* src = reinterpret_cast<const float4*>(conf + (size_t)blk * CHUNK);
    float4* dst = reinterpret_cast<float4*>(lds);
    for (int i = t; i < CHUNK / 4; i += 256) dst[i] = src[i];
    __syncthreads();

    const int la = t >> 2, sub = t & 3;
    const int quad = blk * APB + la;           // global anchor b*NA + a
    const float* crow = lds + la * 81;
    float best = -3.0e38f; int bc = 255;
    for (int c = sub; c <= NCLS; c += 4) {
        if (c == 0) continue;                  // background stripped
        float v = crow[c];
        if (v > best) { best = v; bc = c; }    // strict > : first-index tie-break
    }
    for (int m = 1; m <= 2; m <<= 1) {
        float ov = __shfl_xor(best, m);
        int oc = __shfl_xor(bc, m);
        if (ov > best || (ov == best && oc < bc)) { best = ov; bc = oc; }
    }
    float bmaxl = 0.0f;                        // decoded coords: y1 >= 0, safe identity
    if (sub == 0) {
        scores[quad] = 1.0f / (1.0f + expf(-best));
        cls[quad] = (unsigned char)(bc - 1);
        int a = quad % NA;
        float4 rg = reinterpret_cast<const float4*>(reg)[quad];
        float4 an = reinterpret_cast<const float4*>(anch)[a];
        float x1, y1, x2, y2; decode_box(rg, an, x1, y1, x2, y2);
        bmaxl = fmaxf(fmaxf(x1, y1), fmaxf(x2, y2));
    }
    #pragma unroll
    for (int m = 1; m < 64; m <<= 1) bmaxl = fmaxf(bmaxl, __shfl_xor(bmaxl, m));
    if ((t & 63) == 0) groupmax[blk * 4 + (t >> 6)] = bmaxl;
}

// block-wide inclusive SUFFIX scan over 1024 values; result into outarr[t].
__device__ __forceinline__ void suffix_scan_1024(uint32_t v, int t,
                                                 uint32_t* wtot, uint32_t* outarr) {
    uint32_t r = v;
    const int lane = t & 63, w = t >> 6;
    #pragma unroll
    for (int m = 1; m < 64; m <<= 1) {
        uint32_t o = __shfl_down(r, m);
        if (lane + m < 64) r += o;
    }
    if (lane == 0) wtot[w] = r;
    __syncthreads();
    if (t < 16) {
        uint32_t v0 = wtot[t], x = v0;
        #pragma unroll
        for (int m = 1; m < 16; m <<= 1) {
            uint32_t o = __shfl_down(x, m);
            if (t + m < 16) x += o;
        }
        wtot[t] = x - v0;                      // exclusive suffix of wave totals
    }
    __syncthreads();
    outarr[t] = r + wtot[w];
    __syncthreads();
}

// Phase 2: one block/image. Radix-select top >=NSEL; barrier-free rank sort;
// symmetric 512x512 suppression mask; Jacobi-fixpoint parallel greedy NMS
// (exact: stable => unique greedy fixpoint); popcount-based order/slots.
__global__ __launch_bounds__(1024) void phase2_kernel(
    const float* __restrict__ reg, const float* __restrict__ anch,
    const float* __restrict__ scores, const unsigned char* __restrict__ cls,
    const float* __restrict__ groupmax, float* __restrict__ out)
{
    __shared__ uint64_t s_mask[512 * MROW];   // 36.9KB  alias: hist u32[8192]
    __shared__ float4   s_boxo[512];          // 8KB     alias: fhist u32[2048]
    __shared__ uint64_t s_keys[MKEYS];        // 16KB unsorted; alias csum u32[1024]
    __shared__ uint64_t s_skeys[MKEYS];       // 16KB sorted
    __shared__ float4   s_keptbox[TOPK];      // fallback only
    __shared__ float    s_areao[512];
    __shared__ uint64_t s_clsmask[NCLS][8];   // 5KB keep-bit mask per class
    __shared__ uint32_t s_ccount[NCLS];
    __shared__ uint32_t s_wtot[16];
    __shared__ uint32_t s_shv[8];
    __shared__ float    s_bmaxarr[16];
    __shared__ float    s_offm;
    __shared__ uint8_t  s_clsl[512];
    __shared__ uint64_t s_K[8], s_newK[8];
    __shared__ uint32_t s_chg;

    uint32_t* hist  = (uint32_t*)s_mask;
    uint32_t* fhist = (uint32_t*)s_boxo;
    uint32_t* csum  = (uint32_t*)s_keys;

    const int b = blockIdx.x;
    const int t = threadIdx.x;
    const float* sc = scores + (size_t)b * NA;
    const float4* sc4 = reinterpret_cast<const float4*>(sc);

    // ---- init
    for (int i = t; i < 8192; i += 1024) hist[i] = 0;
    if (t < 8) s_shv[t] = 0;
    __syncthreads();

    // ---- per-image box max from precomputed group maxes (12KB)
    {
        const float* gm = groupmax + (size_t)b * NGRP;
        float wm = 0.0f;
        for (int i = t; i < NGRP; i += 1024) wm = fmaxf(wm, gm[i]);
        #pragma unroll
        for (int m = 1; m < 64; m <<= 1) wm = fmaxf(wm, __shfl_xor(wm, m));
        if ((t & 63) == 0) s_bmaxarr[t >> 6] = wm;
    }

    // ---- Pass A: coarse histogram (bits>>17), float4
    #define HIST1(s) { if ((s) > CONF_T) atomicAdd(&hist[__float_as_uint(s) >> 17], 1u); }
    for (int i = t; i < NA4; i += 1024) {
        float4 s4 = sc4[i];
        HIST1(s4.x) HIST1(s4.y) HIST1(s4.z) HIST1(s4.w)
    }
    __syncthreads();

    // ---- coarse crossing via parallel suffix scan over 1024 chunk-sums
    uint32_t v8 = 0;
    #pragma unroll
    for (int k = 0; k < 8; ++k) v8 += hist[t * 8 + k];
    suffix_scan_1024(v8, t, s_wtot, csum);
    {
        uint32_t sIn = csum[t];
        uint32_t sNext = (t == 1023) ? 0u : csum[t + 1];
        if (sIn >= NSEL && sNext < NSEL) { s_shv[0] = (uint32_t)t; s_shv[1] = sNext; s_shv[2] = 1; }
    }
    __syncthreads();
    for (int i = t; i < 2048; i += 1024) fhist[i] = 0;
    if (t == 0) {
        float mx = s_bmaxarr[0];
        #pragma unroll
        for (int k = 1; k < 16; ++k) mx = fmaxf(mx, s_bmaxarr[k]);
        s_offm = mx + 1.0f;                    // jnp.max(boxes) + 1
        if (s_shv[2]) {
            uint32_t chunk = s_shv[0], run2 = s_shv[1]; int cb = -1; uint32_t ab = 0;
            for (int k = 7; k >= 0; --k) {
                uint32_t v = hist[chunk * 8 + k];
                if (cb < 0 && run2 + v >= NSEL) { cb = (int)(chunk * 8 + k); ab = run2; }
                run2 += v;
            }
            s_shv[0] = (uint32_t)cb; s_shv[1] = ab;
        }
    }
    __syncthreads();

    const uint32_t found = s_shv[2], cbin = s_shv[0], above = s_shv[1];
    // ---- fine histogram ((bits>>6)&2047 within coarse bin), float4
    #define FHIST1(s) { if ((s) > CONF_T) { uint32_t _b = __float_as_uint(s); \
        if ((_b >> 17) == cbin) atomicAdd(&fhist[(_b >> 6) & 2047u], 1u); } }
    if (found) {
        for (int i = t; i < NA4; i += 1024) {
            float4 s4 = sc4[i];
            FHIST1(s4.x) FHIST1(s4.y) FHIST1(s4.z) FHIST1(s4.w)
        }
    }
    __syncthreads();
    uint32_t fv = fhist[2 * t] + fhist[2 * t + 1];
    suffix_scan_1024(fv, t, s_wtot, csum);
    if (found) {
        uint32_t sIn = csum[t] + above;
        uint32_t sNext = ((t == 1023) ? 0u : csum[t + 1]) + above;
        if (sIn >= NSEL && sNext < NSEL) { s_shv[5] = (uint32_t)t; s_shv[6] = sNext; }
    }
    __syncthreads();
    if (t == 0) {
        if (found) {
            uint32_t pc = s_shv[5], ab2 = s_shv[6];
            uint32_t v1 = fhist[pc * 2 + 1];
            uint32_t fbin = (ab2 + v1 >= NSEL) ? (pc * 2 + 1) : (pc * 2);
            s_shv[3] = (cbin << 11) | fbin;
        } else s_shv[3] = 0;
    }
    __syncthreads();

    // ---- gather candidates (score bits >> 6) >= T
    const uint32_t T = s_shv[3];
    #define GATH1(s, g) { if ((s) > CONF_T) { uint32_t _b = __float_as_uint(s); \
        if ((_b >> 6) >= T) { uint32_t _p = atomicAdd(&s_shv[4], 1u); \
            if (_p < MKEYS) s_keys[_p] = ((uint64_t)_b << 32) | \
                (uint64_t)(0xFFFFFFFFu - (uint32_t)(g)); } } }
    for (int i = t; i < NA4; i += 1024) {
        float4 s4 = sc4[i];
        GATH1(s4.x, 4 * i)     GATH1(s4.y, 4 * i + 1)
        GATH1(s4.z, 4 * i + 2) GATH1(s4.w, 4 * i + 3)
    }
    __syncthreads();

    uint32_t nG = s_shv[4]; if (nG > MKEYS) nG = MKEYS;
    const int lim = (nG < 512u) ? (int)nG : 512;

    // ---- rank sort descending (keys unique via index); broadcast reads, 1 barrier
    {
        uint64_t k0 = (t < (int)nG) ? s_keys[t] : 0ull;
        uint64_t k1 = (t + 1024 < (int)nG) ? s_keys[t + 1024] : 0ull;
        uint32_t r0 = 0, r1 = 0;
        for (uint32_t i = 0; i < nG; ++i) {
            uint64_t kv = s_keys[i];
            r0 += (kv > k0);
            r1 += (kv > k1);
        }
        if (t < (int)nG) s_skeys[r0] = k0;
        if (t + 1024 < (int)nG) s_skeys[r1] = k1;
    }
    __syncthreads();

    // ---- prep first 512: offset boxes, areas, classes
    const float offm = s_offm;
    if (t < 512) {
        if (t < lim) {
            uint64_t key = s_skeys[t];
            uint32_t g = 0xFFFFFFFFu - (uint32_t)key;
            size_t qi = (size_t)b * NA + g;
            int c = (int)cls[qi];
            s_clsl[t] = (uint8_t)c;
            float4 rg = reinterpret_cast<const float4*>(reg)[qi];
            float4 an = reinterpret_cast<const float4*>(anch)[g];
            float x1, y1, x2, y2; decode_box(rg, an, x1, y1, x2, y2);
            float off = (float)c * offm;
            float4 bo = make_float4(x1 + off, y1 + off, x2 + off, y2 + off);
            s_boxo[t] = bo;
            s_areao[t] = (bo.z - bo.x) * (bo.w - bo.y);
        } else {
            s_clsl[t] = 0;
            s_boxo[t] = make_float4(0.f, 0.f, 0.f, 0.f);
            s_areao[t] = 0.f;
        }
    }
    // init K = all candidates < lim alive
    if (t < 8) {
        int lo = t * 64, n = lim - lo;
        s_K[t] = (n >= 64) ? ~0ull : (n > 0 ? ((~0ull) >> (64 - n)) : 0ull);
    }
    __syncthreads();

    // ---- suppression mask (symmetric): s_mask[i*MROW+w] = sup(i, 64w..64w+63)
    {
        const int i = t & 511;
        const float4 bi = s_boxo[i];
        const float aI = s_areao[i];
        for (int w = (t >> 9); w < 8; w += 2) {
            uint64_t m = 0ull;
            for (int jj = 0; jj < 64; ++jj) {
                float4 bj = s_boxo[w * 64 + jj];       // wave-broadcast read
                float ix1 = fmaxf(bi.x, bj.x), iy1 = fmaxf(bi.y, bj.y);
                float ix2 = fminf(bi.z, bj.z), iy2 = fminf(bi.w, bj.w);
                float inter = fmaxf(ix2 - ix1, 0.f) * fmaxf(iy2 - iy1, 0.f);
                float uni = aI + s_areao[w * 64 + jj] - inter;
                if (uni > 0.f && inter + inter > uni) m |= (1ull << jj);
            }
            s_mask[(size_t)i * MROW + w] = m;
        }
    }
    __syncthreads();

    // ---- Jacobi fixpoint greedy NMS: keep[j] = !exists i<j: keep[i] & sup(i,j).
    // Stable iterate == unique fixpoint == exact greedy. Converges in chain-depth+2.
    {
        const int jw = t >> 6, jb = t & 63;
        const uint64_t below = (jb == 0) ? 0ull : ((~0ull) >> (64 - jb));
        const uint64_t* mrow = s_mask + (size_t)(t & 511) * MROW;
        for (int round = 0; round < 600; ++round) {
            bool nb = false;
            if (t < 512) {
                uint64_t dead = 0ull;
                #pragma unroll
                for (int w = 0; w < 8; ++w) {
                    uint64_t mm = mrow[w] & s_K[w];
                    if (w < jw) dead |= mm;
                    else if (w == jw) dead |= (mm & below);
                }
                nb = (dead == 0ull) && (t < lim);
            }
            uint64_t bal = __ballot(nb);
            if (t < 512 && (t & 63) == 0) s_newK[jw] = bal;
            if (t == 0) s_chg = 0;
            __syncthreads();
            if (t < 8 && s_newK[t] != s_K[t]) atomicOr(&s_chg, 1u);
            __syncthreads();
            if (!s_chg) break;                 // uniform
            if (t < 8) s_K[t] = s_newK[t];
            __syncthreads();
        }
    }

    // ---- per-class keep masks + counts + total keeps
    if (t < NCLS * 8) ((uint64_t*)s_clsmask)[t] = 0ull;
    __syncthreads();
    if (t < 512 && ((s_K[t >> 6] >> (t & 63)) & 1ull))
        atomicOr(&s_clsmask[s_clsl[t]][t >> 6], 1ull << (t & 63));
    __syncthreads();
    if (t < NCLS) {
        uint32_t n = 0;
        #pragma unroll
        for (int w = 0; w < 8; ++w) n += (uint32_t)__popcll(s_clsmask[t][w]);
        s_ccount[t] = n;
    }
    if (t == 0) {
        uint32_t n = 0;
        #pragma unroll
        for (int w = 0; w < 8; ++w) n += (uint32_t)__popcll(s_K[w]);
        s_shv[7] = n;
    }
    __syncthreads();

    // ---- parallel output of first TOPK keeps (order & slot via masked popcounts)
    {
        const int jw = t >> 6, jb = t & 63;
        bool kept = (t < 512) && ((s_K[jw] >> jb) & 1ull);
        if (kept) {
            const uint64_t below = (jb == 0) ? 0ull : ((~0ull) >> (64 - jb));
            uint32_t ord = (uint32_t)__popcll(s_K[jw] & below);
            for (int w = 0; w < jw; ++w) ord += (uint32_t)__popcll(s_K[w]);
            if (ord < TOPK) {
                int c = (int)s_clsl[t];
                const uint64_t* cm = s_clsmask[c];
                uint32_t slot = (uint32_t)__popcll(cm[jw] & below);
                for (int w = 0; w < jw; ++w) slot += (uint32_t)__popcll(cm[w]);
                uint64_t key = s_skeys[t];
                uint32_t g = 0xFFFFFFFFu - (uint32_t)key;
                float scv = __uint_as_float((uint32_t)(key >> 32));
                size_t qi = (size_t)b * NA + g;
                float4 rg = reinterpret_cast<const float4*>(reg)[qi];
                float4 an = reinterpret_cast<const float4*>(anch)[g];
                float x1, y1, x2, y2; decode_box(rg, an, x1, y1, x2, y2);
                float* o = out + (((size_t)b * (NCLS + 1) + (size_t)(c + 1)) * TOPK + slot) * 5;
                o[0] = scv; o[1] = x1; o[2] = y1; o[3] = x2; o[4] = y2;
                s_keptbox[ord] = s_boxo[t];    // for fallback
            }
        }
    }
    __syncthreads();

    // ---- serial fallback past 512 (exactness insurance; ~never taken)
    if (t == 0) {
        uint32_t nk = s_shv[7];
        if (nk < TOPK && nG > (uint32_t)lim) {
            for (uint32_t ci = (uint32_t)lim; ci < nG && nk < TOPK; ++ci) {
                uint64_t key = s_skeys[ci];
                uint32_t g = 0xFFFFFFFFu - (uint32_t)key;
                size_t qi = (size_t)b * NA + g;
                int c = (int)cls[qi];
                float4 rg = reinterpret_cast<const float4*>(reg)[qi];
                float4 an = reinterpret_cast<const float4*>(anch)[g];
                float x1, y1, x2, y2; decode_box(rg, an, x1, y1, x2, y2);
                float off = (float)c * offm;
                float4 bo = make_float4(x1 + off, y1 + off, x2 + off, y2 + off);
                float aB2 = (bo.z - bo.x) * (bo.w - bo.y);
                bool sup = false;
                for (uint32_t k2 = 0; k2 < nk && !sup; ++k2) {
                    float4 kb = s_keptbox[k2];
                    float aK = (kb.z - kb.x) * (kb.w - kb.y);
                    float ix1 = fmaxf(bo.x, kb.x), iy1 = fmaxf(bo.y, kb.y);
                    float ix2 = fminf(bo.z, kb.z), iy2 = fminf(bo.w, kb.w);
                    float inter = fmaxf(ix2 - ix1, 0.f) * fmaxf(iy2 - iy1, 0.f);
                    float uni = aB2 + aK - inter;
                    sup = (uni > 0.f && inter + inter > uni);
                }
                if (!sup) {
                    uint32_t slot = s_ccount[c]; s_ccount[c] = slot + 1;
                    float scv = __uint_as_float((uint32_t)(key >> 32));
                    float* o = out + (((size_t)b * (NCLS + 1) + (size_t)(c + 1)) * TOPK + slot) * 5;
                    o[0] = scv; o[1] = x1; o[2] = y1; o[3] = x2; o[4] = y2;
                    s_keptbox[nk] = bo;
                    ++nk;
                }
            }
        }
    }
}

extern "C" void kernel_launch(void* const* d_in, const int* in_sizes, int n_in,
                              void* d_out, int out_size, void* d_ws, size_t ws_size,
                              hipStream_t stream)
{
    const float* conf = (const float*)d_in[0];   // [B, A, 81] f32
    const float* reg  = (const float*)d_in[1];   // [B, A, 4]  f32
    const float* anch = (const float*)d_in[2];   // [A, 4]     f32
    float* out = (float*)d_out;                  // [B, 81, 200, 5] f32

    char* ws = (char*)d_ws;
    float* scores = (float*)ws;                                       // NB*NA f32
    unsigned char* cls = (unsigned char*)(ws + (size_t)NB * NA * 4);  // NB*NA u8
    float* groupmax = (float*)(ws + (size_t)NB * NA * 5);             // NB*NGRP f32

    hipMemsetAsync(d_out, 0, (size_t)out_size * sizeof(float), stream);

    int blocks = (NB * NA) / APB;        // 6138 exact
    phase1_kernel<<<blocks, 256, 0, stream>>>(conf, reg, anch, scores, cls, groupmax);
    phase2_kernel<<<NB, 1024, 0, stream>>>(reg, anch, scores, cls, groupmax, out);
}

// Round 6
// 72.955 us; speedup vs baseline: 7.7430x; 1.6193x over previous
//
#include <hip/hip_runtime.h>
#include <stdint.h>

#define NCLS 80
#define TOPK 200
#define CONF_T 0.05f
#define CROPF 300.0f
#define NA 49104
#define NB 8
#define NSEL 256
#define MKEYS 4096
#define APB 64
#define CHUNK (APB * 81)
#define NGRP (NA / 16)          // 3069 16-anchor groups per image (16 | NA)
#define MROW 5                  // mask row stride in u64 (odd-ish: conflict-light)

__device__ __forceinline__ void decode_box(const float4 rg, const float4 an,
                                           float& x1, float& y1, float& x2, float& y2) {
    // anchors: (ymin, xmin, ymax, xmax); reg: (dy, dx, dh, dw)
    float yca = (an.x + an.z) * 0.5f;
    float xca = (an.y + an.w) * 0.5f;
    float ha = an.z - an.x;
    float wa = an.w - an.y;
    float w = expf(rg.w) * wa;
    float h = expf(rg.z) * ha;
    float yc = rg.x * ha + yca;
    float xc = rg.y * wa + xca;
    x1 = fmaxf(xc - w * 0.5f, 0.0f) / CROPF;
    y1 = fmaxf(yc - h * 0.5f, 0.0f) / CROPF;
    x2 = fminf(xc + w * 0.5f, CROPF - 1.0f) / CROPF;
    y2 = fminf(yc + h * 0.5f, CROPF - 1.0f) / CROPF;
}

__device__ __forceinline__ float rlf(float v, int l) {
    return __int_as_float(__builtin_amdgcn_readlane(__float_as_int(v), l));
}

// Phase 1: conf -> (scores, cls); per-16-anchor-group float2{max score, max box coord}
// (wave-local reduce, no atomics; 16 | NA so groups never straddle images).
__global__ __launch_bounds__(256) void phase1_kernel(
    const float* __restrict__ conf, const float* __restrict__ reg,
    const float* __restrict__ anch, float* __restrict__ scores,
    unsigned char* __restrict__ cls, float2* __restrict__ gm2)
{
    __shared__ float lds[CHUNK];
    const int blk = blockIdx.x, t = threadIdx.x;
    const float4* src = reinterpret_cast<const float4*>(conf + (size_t)blk * CHUNK);
    float4* dst = reinterpret_cast<float4*>(lds);
    for (int i = t; i < CHUNK / 4; i += 256) dst[i] = src[i];
    __syncthreads();

    const int la = t >> 2, sub = t & 3;
    const int quad = blk * APB + la;           // global anchor b*NA + a
    const float* crow = lds + la * 81;
    float best = -3.0e38f; int bc = 255;
    for (int c = sub; c <= NCLS; c += 4) {
        if (c == 0) continue;                  // background stripped
        float v = crow[c];
        if (v > best) { best = v; bc = c; }    // strict > : first-index tie-break
    }
    for (int m = 1; m <= 2; m <<= 1) {
        float ov = __shfl_xor(best, m);
        int oc = __shfl_xor(bc, m);
        if (ov > best || (ov == best && oc < bc)) { best = ov; bc = oc; }
    }
    float bmaxl = 0.0f;                        // decoded coords: y1 >= 0, safe identity
    if (sub == 0) {
        scores[quad] = 1.0f / (1.0f + expf(-best));
        cls[quad] = (unsigned char)(bc - 1);
        int a = quad % NA;
        float4 rg = reinterpret_cast<const float4*>(reg)[quad];
        float4 an = reinterpret_cast<const float4*>(anch)[a];
        float x1, y1, x2, y2; decode_box(rg, an, x1, y1, x2, y2);
        bmaxl = fmaxf(fmaxf(x1, y1), fmaxf(x2, y2));
    }
    float wbest = best;                        // group max logit (monotone -> score max)
    #pragma unroll
    for (int m = 1; m < 64; m <<= 1) {
        wbest = fmaxf(wbest, __shfl_xor(wbest, m));
        bmaxl = fmaxf(bmaxl, __shfl_xor(bmaxl, m));
    }
    if ((t & 63) == 0)
        gm2[blk * 4 + (t >> 6)] = make_float2(1.0f / (1.0f + expf(-wbest)), bmaxl);
}

// block-wide inclusive SUFFIX scan over 1024 values; result into outarr[t].
__device__ __forceinline__ void suffix_scan_1024(uint32_t v, int t,
                                                 uint32_t* wtot, uint32_t* outarr) {
    uint32_t r = v;
    const int lane = t & 63, w = t >> 6;
    #pragma unroll
    for (int m = 1; m < 64; m <<= 1) {
        uint32_t o = __shfl_down(r, m);
        if (lane + m < 64) r += o;
    }
    if (lane == 0) wtot[w] = r;
    __syncthreads();
    if (t < 16) {
        uint32_t v0 = wtot[t], x = v0;
        #pragma unroll
        for (int m = 1; m < 16; m <<= 1) {
            uint32_t o = __shfl_down(x, m);
            if (t + m < 16) x += o;
        }
        wtot[t] = x - v0;                      // exclusive suffix of wave totals
    }
    __syncthreads();
    outarr[t] = r + wtot[w];
    __syncthreads();
}

// Phase 2: one block/image. Radix-select on 3069 GROUP maxes; gather only
// qualified groups' anchors; readlane rank sort; readlane 256x256 mask build;
// Jacobi-fixpoint exact greedy NMS; popcount output; exact serial fallback.
__global__ __launch_bounds__(1024) void phase2_kernel(
    const float* __restrict__ reg, const float* __restrict__ anch,
    const float* __restrict__ scores, const unsigned char* __restrict__ cls,
    const float2* __restrict__ gm2, float* __restrict__ out)
{
    __shared__ uint64_t s_keys[MKEYS];        // 32KB  alias: hist u32[8192]
    __shared__ uint64_t s_skeys[MKEYS];       // 32KB  alias: csum u32[1024]
    __shared__ uint64_t s_mask[256 * MROW];   // 10KB
    __shared__ float4   s_boxo[256];          // 4KB
    __shared__ float    s_areao[256];
    __shared__ float    s_gm[NGRP + 3];       // 12KB group score maxes
    __shared__ uint32_t s_glist[2048];        // 8KB   alias: fhist u32[2048]
    __shared__ float4   s_keptbox[TOPK];      // fallback only
    __shared__ uint64_t s_clsmask[NCLS][4];   // keep-bit mask per class
    __shared__ uint32_t s_ccount[NCLS];
    __shared__ uint32_t s_wtot[16];
    __shared__ uint32_t s_shv[12];
    __shared__ float    s_bmaxarr[16];
    __shared__ float    s_offm;
    __shared__ uint8_t  s_clsl[256];
    __shared__ uint64_t s_K[4], s_newK[4];
    __shared__ uint32_t s_chg;

    uint32_t* hist  = (uint32_t*)s_keys;
    uint32_t* fhist = s_glist;
    uint32_t* csum  = (uint32_t*)s_skeys;

    const int b = blockIdx.x;
    const int t = threadIdx.x;

    // ---- init
    for (int i = t; i < 8192; i += 1024) hist[i] = 0;
    if (t < 12) s_shv[t] = 0;
    __syncthreads();

    // ---- step 1: load group maxes; coarse hist (bits>>17) + box max
    {
        const float2* gmb = gm2 + (size_t)b * NGRP;
        float wm = 0.0f;
        for (int i = t; i < NGRP; i += 1024) {
            float2 v = gmb[i];
            s_gm[i] = v.x;
            wm = fmaxf(wm, v.y);
            if (v.x > CONF_T) atomicAdd(&hist[__float_as_uint(v.x) >> 17], 1u);
        }
        #pragma unroll
        for (int m = 1; m < 64; m <<= 1) wm = fmaxf(wm, __shfl_xor(wm, m));
        if ((t & 63) == 0) s_bmaxarr[t >> 6] = wm;
    }
    __syncthreads();

    // ---- coarse crossing via suffix scan over 1024 chunk-sums
    uint32_t v8 = 0;
    #pragma unroll
    for (int k = 0; k < 8; ++k) v8 += hist[t * 8 + k];
    suffix_scan_1024(v8, t, s_wtot, csum);
    {
        uint32_t sIn = csum[t];
        uint32_t sNext = (t == 1023) ? 0u : csum[t + 1];
        if (sIn >= NSEL && sNext < NSEL) { s_shv[0] = (uint32_t)t; s_shv[1] = sNext; s_shv[2] = 1; }
    }
    __syncthreads();
    for (int i = t; i < 2048; i += 1024) fhist[i] = 0;
    if (t == 0) {
        float mx = s_bmaxarr[0];
        #pragma unroll
        for (int k = 1; k < 16; ++k) mx = fmaxf(mx, s_bmaxarr[k]);
        s_offm = mx + 1.0f;                    // jnp.max(boxes) + 1
        if (s_shv[2]) {
            uint32_t chunk = s_shv[0], run2 = s_shv[1]; int cb = -1; uint32_t ab = 0;
            for (int k = 7; k >= 0; --k) {
                uint32_t v = hist[chunk * 8 + k];
                if (cb < 0 && run2 + v >= NSEL) { cb = (int)(chunk * 8 + k); ab = run2; }
                run2 += v;
            }
            s_shv[0] = (uint32_t)cb; s_shv[1] = ab;
        }
    }
    __syncthreads();

    const uint32_t found = s_shv[2], cbin = s_shv[0], above = s_shv[1];
    // ---- fine hist on group maxes in cbin; zero keys (hist now dead)
    for (int i = t; i < MKEYS; i += 1024) s_keys[i] = 0ull;
    if (found) {
        for (int i = t; i < NGRP; i += 1024) {
            float s = s_gm[i];
            if (s > CONF_T) {
                uint32_t bits = __float_as_uint(s);
                if ((bits >> 17) == cbin) atomicAdd(&fhist[(bits >> 6) & 2047u], 1u);
            }
        }
    }
    __syncthreads();
    uint32_t fv = fhist[2 * t] + fhist[2 * t + 1];
    suffix_scan_1024(fv, t, s_wtot, csum);
    if (found) {
        uint32_t sIn = csum[t] + above;
        uint32_t sNext = ((t == 1023) ? 0u : csum[t + 1]) + above;
        if (sIn >= NSEL && sNext < NSEL) { s_shv[5] = (uint32_t)t; s_shv[6] = sNext; }
    }
    __syncthreads();
    if (t == 0) {
        if (found) {
            uint32_t pc = s_shv[5], ab2 = s_shv[6];
            uint32_t v1 = fhist[pc * 2 + 1];
            uint32_t fbin = (ab2 + v1 >= NSEL) ? (pc * 2 + 1) : (pc * 2);
            s_shv[3] = (cbin << 11) | fbin;
        } else s_shv[3] = 0;
    }
    __syncthreads();

    // ---- qualify groups (gmax >= T); fhist dead -> glist
    const uint32_t T = s_shv[3];
    for (int i = t; i < NGRP; i += 1024) {
        float s = s_gm[i];
        if (s > CONF_T && (__float_as_uint(s) >> 6) >= T) {
            uint32_t p = atomicAdd(&s_shv[8], 1u);
            if (p < 2048u) s_glist[p] = (uint32_t)i;
        }
    }
    __syncthreads();
    uint32_t ngl = s_shv[8]; if (ngl > 2048u) ngl = 2048u;

    // ---- gather candidate anchors from qualified groups only
    {
        const float4* sc4 = reinterpret_cast<const float4*>(scores + (size_t)b * NA);
        #define GATH1(s, g) { if ((s) > CONF_T) { uint32_t _b = __float_as_uint(s); \
            if ((_b >> 6) >= T) { uint32_t _p = atomicAdd(&s_shv[4], 1u); \
                if (_p < MKEYS) s_keys[_p] = ((uint64_t)_b << 32) | \
                    (uint64_t)(0xFFFFFFFFu - (uint32_t)(g)); } } }
        for (int idx = t; idx < (int)(ngl * 4); idx += 1024) {
            uint32_t gi = s_glist[idx >> 2];
            int q = idx & 3;
            float4 s4 = sc4[gi * 4 + q];
            uint32_t g0 = gi * 16 + (uint32_t)q * 4;
            GATH1(s4.x, g0)     GATH1(s4.y, g0 + 1)
            GATH1(s4.z, g0 + 2) GATH1(s4.w, g0 + 3)
        }
    }
    __syncthreads();
    uint32_t nGa = s_shv[4]; if (nGa > MKEYS) nGa = MKEYS;
    const int lim = (nGa < 256u) ? (int)nGa : 256;

    // ---- rank sort descending via readlane broadcast (keys unique via ~idx)
    {
        const int lane = t & 63;
        const uint32_t nch = (nGa + 63) >> 6;
        for (int s = 0; s < 4; ++s) {
            int kid = t + s * 1024;
            bool act = kid < (int)nGa;
            if (__ballot(act) == 0ull) continue;
            uint64_t my = act ? s_keys[kid] : ~0ull;
            uint32_t r = 0;
            for (uint32_t ch = 0; ch < nch; ++ch) {
                uint64_t kc = s_keys[ch * 64 + lane];   // pad region zeroed
                uint32_t clo = (uint32_t)kc, chi = (uint32_t)(kc >> 32);
                for (int jj = 0; jj < 64; ++jj) {
                    uint32_t olo = (uint32_t)__builtin_amdgcn_readlane((int)clo, jj);
                    uint32_t ohi = (uint32_t)__builtin_amdgcn_readlane((int)chi, jj);
                    uint64_t ok = ((uint64_t)ohi << 32) | olo;
                    r += (ok > my) ? 1u : 0u;
                }
            }
            if (act) s_skeys[r] = my;
        }
    }
    __syncthreads();

    // ---- prep first 256: offset boxes, areas, classes; init K; zero clsmask
    const float offm = s_offm;
    if (t < 256) {
        if (t < lim) {
            uint64_t key = s_skeys[t];
            uint32_t g = 0xFFFFFFFFu - (uint32_t)key;
            size_t qi = (size_t)b * NA + g;
            int c = (int)cls[qi];
            s_clsl[t] = (uint8_t)c;
            float4 rg = reinterpret_cast<const float4*>(reg)[qi];
            float4 an = reinterpret_cast<const float4*>(anch)[g];
            float x1, y1, x2, y2; decode_box(rg, an, x1, y1, x2, y2);
            float off = (float)c * offm;
            float4 bo = make_float4(x1 + off, y1 + off, x2 + off, y2 + off);
            s_boxo[t] = bo;
            s_areao[t] = (bo.z - bo.x) * (bo.w - bo.y);
        } else {
            s_clsl[t] = 0;
            s_boxo[t] = make_float4(0.f, 0.f, 0.f, 0.f);
            s_areao[t] = 0.f;
        }
    }
    if (t < 4) {
        int lo = t * 64, n = lim - lo;
        s_K[t] = (n >= 64) ? ~0ull : (n > 0 ? ((~0ull) >> (64 - n)) : 0ull);
    }
    if (t < NCLS * 4) ((uint64_t*)s_clsmask)[t] = 0ull;
    __syncthreads();

    // ---- 256x256 suppression mask, register-resident via readlane
    {
        const int wv = t >> 6, lane = t & 63;
        const int rbase = (wv & 3) * 64, c = wv >> 2;
        const int i = rbase + lane;
        float4 bi = s_boxo[i];
        float aI = s_areao[i];
        float4 vj = s_boxo[c * 64 + lane];
        float vA = s_areao[c * 64 + lane];
        uint64_t m = 0ull;
        for (int jj = 0; jj < 64; ++jj) {
            float bx1 = rlf(vj.x, jj), by1 = rlf(vj.y, jj);
            float bx2 = rlf(vj.z, jj), by2 = rlf(vj.w, jj);
            float aJ  = rlf(vA, jj);
            float ix1 = fmaxf(bi.x, bx1), iy1 = fmaxf(bi.y, by1);
            float ix2 = fminf(bi.z, bx2), iy2 = fminf(bi.w, by2);
            float inter = fmaxf(ix2 - ix1, 0.f) * fmaxf(iy2 - iy1, 0.f);
            float uni = aI + aJ - inter;
            if (uni > 0.f && inter + inter > uni) m |= (1ull << jj);
        }
        s_mask[(size_t)i * MROW + c] = m;
    }
    __syncthreads();

    // ---- Jacobi fixpoint greedy NMS (exact: stable iterate == greedy fixpoint)
    {
        const int jw = (t >> 6) & 3, jb = t & 63;
        const uint64_t below = (jb == 0) ? 0ull : ((~0ull) >> (64 - jb));
        const uint64_t* mrow = s_mask + (size_t)(t & 255) * MROW;
        for (int round = 0; round < 300; ++round) {
            bool nb = false;
            if (t < 256) {
                uint64_t dead = 0ull;
                #pragma unroll
                for (int w = 0; w < 4; ++w) {
                    uint64_t mm = mrow[w] & s_K[w];
                    if (w < jw) dead |= mm;
                    else if (w == jw) dead |= (mm & below);
                }
                nb = (dead == 0ull) && (t < lim);
            }
            uint64_t bal = __ballot(nb);
            if (t < 256 && (t & 63) == 0) s_newK[jw] = bal;
            if (t == 0) s_chg = 0;
            __syncthreads();
            if (t < 4 && s_newK[t] != s_K[t]) atomicOr(&s_chg, 1u);
            __syncthreads();
            if (!s_chg) break;
            if (t < 4) s_K[t] = s_newK[t];
            __syncthreads();
        }
    }

    // ---- per-class keep masks + counts + total keeps
    if (t < 256 && ((s_K[(t >> 6) & 3] >> (t & 63)) & 1ull))
        atomicOr(&s_clsmask[s_clsl[t]][(t >> 6) & 3], 1ull << (t & 63));
    __syncthreads();
    if (t < NCLS) {
        uint32_t n = 0;
        #pragma unroll
        for (int w = 0; w < 4; ++w) n += (uint32_t)__popcll(s_clsmask[t][w]);
        s_ccount[t] = n;
    }
    if (t == 0) {
        uint32_t n = 0;
        #pragma unroll
        for (int w = 0; w < 4; ++w) n += (uint32_t)__popcll(s_K[w]);
        s_shv[7] = n;
    }
    __syncthreads();

    // ---- parallel output of first TOPK keeps (order & slot via masked popcounts)
    {
        const int jw = (t >> 6) & 3, jb = t & 63;
        bool kept = (t < 256) && ((s_K[jw] >> jb) & 1ull);
        if (kept) {
            const uint64_t below = (jb == 0) ? 0ull : ((~0ull) >> (64 - jb));
            uint32_t ord = (uint32_t)__popcll(s_K[jw] & below);
            for (int w = 0; w < jw; ++w) ord += (uint32_t)__popcll(s_K[w]);
            if (ord < TOPK) {
                int c = (int)s_clsl[t];
                const uint64_t* cm = s_clsmask[c];
                uint32_t slot = (uint32_t)__popcll(cm[jw] & below);
                for (int w = 0; w < jw; ++w) slot += (uint32_t)__popcll(cm[w]);
                uint64_t key = s_skeys[t];
                uint32_t g = 0xFFFFFFFFu - (uint32_t)key;
                float scv = __uint_as_float((uint32_t)(key >> 32));
                size_t qi = (size_t)b * NA + g;
                float4 rg = reinterpret_cast<const float4*>(reg)[qi];
                float4 an = reinterpret_cast<const float4*>(anch)[g];
                float x1, y1, x2, y2; decode_box(rg, an, x1, y1, x2, y2);
                float* o = out + (((size_t)b * (NCLS + 1) + (size_t)(c + 1)) * TOPK + slot) * 5;
                o[0] = scv; o[1] = x1; o[2] = y1; o[3] = x2; o[4] = y2;
                s_keptbox[ord] = s_boxo[t];    // for fallback
            }
        }
    }
    __syncthreads();

    // ---- serial fallback past lim (exactness insurance; ~never taken)
    if (t == 0) {
        uint32_t nk = s_shv[7];
        if (nk < TOPK && nGa > (uint32_t)lim) {
            for (uint32_t ci = (uint32_t)lim; ci < nGa && nk < TOPK; ++ci) {
                uint64_t key = s_skeys[ci];
                uint32_t g = 0xFFFFFFFFu - (uint32_t)key;
                size_t qi = (size_t)b * NA + g;
                int c = (int)cls[qi];
                float4 rg = reinterpret_cast<const float4*>(reg)[qi];
                float4 an = reinterpret_cast<const float4*>(anch)[g];
                float x1, y1, x2, y2; decode_box(rg, an, x1, y1, x2, y2);
                float off = (float)c * offm;
                float4 bo = make_float4(x1 + off, y1 + off, x2 + off, y2 + off);
                float aB2 = (bo.z - bo.x) * (bo.w - bo.y);
                bool sup = false;
                for (uint32_t k2 = 0; k2 < nk && !sup; ++k2) {
                    float4 kb = s_keptbox[k2];
                    float aK = (kb.z - kb.x) * (kb.w - kb.y);
                    float ix1 = fmaxf(bo.x, kb.x), iy1 = fmaxf(bo.y, kb.y);
                    float ix2 = fminf(bo.z, kb.z), iy2 = fminf(bo.w, kb.w);
                    float inter = fmaxf(ix2 - ix1, 0.f) * fmaxf(iy2 - iy1, 0.f);
                    float uni = aB2 + aK - inter;
                    sup = (uni > 0.f && inter + inter > uni);
                }
                if (!sup) {
                    uint32_t slot = s_ccount[c]; s_ccount[c] = slot + 1;
                    float scv = __uint_as_float((uint32_t)(key >> 32));
                    float* o = out + (((size_t)b * (NCLS + 1) + (size_t)(c + 1)) * TOPK + slot) * 5;
                    o[0] = scv; o[1] = x1; o[2] = y1; o[3] = x2; o[4] = y2;
                    s_keptbox[nk] = bo;
                    ++nk;
                }
            }
        }
    }
}

extern "C" void kernel_launch(void* const* d_in, const int* in_sizes, int n_in,
                              void* d_out, int out_size, void* d_ws, size_t ws_size,
                              hipStream_t stream)
{
    const float* conf = (const float*)d_in[0];   // [B, A, 81] f32
    const float* reg  = (const float*)d_in[1];   // [B, A, 4]  f32
    const float* anch = (const float*)d_in[2];   // [A, 4]     f32
    float* out = (float*)d_out;                  // [B, 81, 200, 5] f32

    char* ws = (char*)d_ws;
    float* scores = (float*)ws;                                       // NB*NA f32
    float2* gm2 = (float2*)(ws + (size_t)NB * NA * 4);                // NB*NGRP float2
    unsigned char* cls = (unsigned char*)(ws + (size_t)NB * NA * 4
                                             + (size_t)NB * NGRP * 8); // NB*NA u8

    hipMemsetAsync(d_out, 0, (size_t)out_size * sizeof(float), stream);

    int blocks = (NB * NA) / APB;        // 6138 exact
    phase1_kernel<<<blocks, 256, 0, stream>>>(conf, reg, anch, scores, cls, gm2);
    phase2_kernel<<<NB, 1024, 0, stream>>>(reg, anch, scores, cls, gm2, out);
}

// Round 7
// 70.754 us; speedup vs baseline: 7.9838x; 1.0311x over previous
//
#include <hip/hip_runtime.h>
#include <stdint.h>

#define NCLS 80
#define TOPK 200
#define CONF_T 0.05f
#define CROPF 300.0f
#define NA 49104
#define NB 8
#define NSEL 256
#define MKEYS 4096
#define APB 64
#define CHUNK (APB * 81)
#define NGRP (NA / 16)          // 3069 16-anchor groups per image (16 | NA)
#define MROW 5                  // mask row stride in u64 (odd-ish: conflict-light)
#define OUTFLO ((NCLS + 1) * TOPK * 5)   // 81000 floats per image, % 4 == 0

__device__ __forceinline__ void decode_box(const float4 rg, const float4 an,
                                           float& x1, float& y1, float& x2, float& y2) {
    // anchors: (ymin, xmin, ymax, xmax); reg: (dy, dx, dh, dw)
    float yca = (an.x + an.z) * 0.5f;
    float xca = (an.y + an.w) * 0.5f;
    float ha = an.z - an.x;
    float wa = an.w - an.y;
    float w = expf(rg.w) * wa;
    float h = expf(rg.z) * ha;
    float yc = rg.x * ha + yca;
    float xc = rg.y * wa + xca;
    x1 = fmaxf(xc - w * 0.5f, 0.0f) / CROPF;
    y1 = fmaxf(yc - h * 0.5f, 0.0f) / CROPF;
    x2 = fminf(xc + w * 0.5f, CROPF - 1.0f) / CROPF;
    y2 = fminf(yc + h * 0.5f, CROPF - 1.0f) / CROPF;
}

__device__ __forceinline__ float rlf(float v, int l) {
    return __int_as_float(__builtin_amdgcn_readlane(__float_as_int(v), l));
}

// Phase 1: conf -> (scores, cls); per-16-anchor-group float2{max score, max box coord}
// (wave-local reduce, no atomics; 16 | NA so groups never straddle images).
__global__ __launch_bounds__(256) void phase1_kernel(
    const float* __restrict__ conf, const float* __restrict__ reg,
    const float* __restrict__ anch, float* __restrict__ scores,
    unsigned char* __restrict__ cls, float2* __restrict__ gm2)
{
    __shared__ float lds[CHUNK];
    const int blk = blockIdx.x, t = threadIdx.x;
    const float4* src = reinterpret_cast<const float4*>(conf + (size_t)blk * CHUNK);
    float4* dst = reinterpret_cast<float4*>(lds);
    for (int i = t; i < CHUNK / 4; i += 256) dst[i] = src[i];
    __syncthreads();

    const int la = t >> 2, sub = t & 3;
    const int quad = blk * APB + la;           // global anchor b*NA + a
    const float* crow = lds + la * 81;
    float best = -3.0e38f; int bc = 255;
    for (int c = sub; c <= NCLS; c += 4) {
        if (c == 0) continue;                  // background stripped
        float v = crow[c];
        if (v > best) { best = v; bc = c; }    // strict > : first-index tie-break
    }
    for (int m = 1; m <= 2; m <<= 1) {
        float ov = __shfl_xor(best, m);
        int oc = __shfl_xor(bc, m);
        if (ov > best || (ov == best && oc < bc)) { best = ov; bc = oc; }
    }
    float bmaxl = 0.0f;                        // decoded coords: y1 >= 0, safe identity
    if (sub == 0) {
        scores[quad] = 1.0f / (1.0f + expf(-best));
        cls[quad] = (unsigned char)(bc - 1);
        int a = quad % NA;
        float4 rg = reinterpret_cast<const float4*>(reg)[quad];
        float4 an = reinterpret_cast<const float4*>(anch)[a];
        float x1, y1, x2, y2; decode_box(rg, an, x1, y1, x2, y2);
        bmaxl = fmaxf(fmaxf(x1, y1), fmaxf(x2, y2));
    }
    float wbest = best;                        // group max logit (monotone -> score max)
    #pragma unroll
    for (int m = 1; m < 64; m <<= 1) {
        wbest = fmaxf(wbest, __shfl_xor(wbest, m));
        bmaxl = fmaxf(bmaxl, __shfl_xor(bmaxl, m));
    }
    if ((t & 63) == 0)
        gm2[blk * 4 + (t >> 6)] = make_float2(1.0f / (1.0f + expf(-wbest)), bmaxl);
}

// block-wide inclusive SUFFIX scan over 1024 values; result into outarr[t].
__device__ __forceinline__ void suffix_scan_1024(uint32_t v, int t,
                                                 uint32_t* wtot, uint32_t* outarr) {
    uint32_t r = v;
    const int lane = t & 63, w = t >> 6;
    #pragma unroll
    for (int m = 1; m < 64; m <<= 1) {
        uint32_t o = __shfl_down(r, m);
        if (lane + m < 64) r += o;
    }
    if (lane == 0) wtot[w] = r;
    __syncthreads();
    if (t < 16) {
        uint32_t v0 = wtot[t], x = v0;
        #pragma unroll
        for (int m = 1; m < 16; m <<= 1) {
            uint32_t o = __shfl_down(x, m);
            if (t + m < 16) x += o;
        }
        wtot[t] = x - v0;                      // exclusive suffix of wave totals
    }
    __syncthreads();
    outarr[t] = r + wtot[w];
    __syncthreads();
}

// Phase 2: one block/image. Self-zeroes its out slice (no rocclr fill kernel).
// Radix-select on 3069 GROUP maxes; gather only qualified groups' anchors;
// readlane rank sort; readlane 256x256 mask build; Jacobi-fixpoint exact
// greedy NMS; popcount output; exact serial fallback.
__global__ __launch_bounds__(1024) void phase2_kernel(
    const float* __restrict__ reg, const float* __restrict__ anch,
    const float* __restrict__ scores, const unsigned char* __restrict__ cls,
    const float2* __restrict__ gm2, float* __restrict__ out)
{
    __shared__ uint64_t s_keys[MKEYS];        // 32KB  alias: hist u32[8192]
    __shared__ uint64_t s_skeys[MKEYS];       // 32KB  alias: csum u32[1024]
    __shared__ uint64_t s_mask[256 * MROW];   // 10KB
    __shared__ float4   s_boxo[256];          // 4KB
    __shared__ float    s_areao[256];
    __shared__ float    s_gm[NGRP + 3];       // 12KB group score maxes
    __shared__ uint32_t s_glist[2048];        // 8KB   alias: fhist u32[2048]
    __shared__ float4   s_keptbox[TOPK];      // fallback only
    __shared__ uint64_t s_clsmask[NCLS][4];   // keep-bit mask per class
    __shared__ uint32_t s_ccount[NCLS];
    __shared__ uint32_t s_wtot[16];
    __shared__ uint32_t s_shv[12];
    __shared__ float    s_bmaxarr[16];
    __shared__ float    s_offm;
    __shared__ uint8_t  s_clsl[256];
    __shared__ uint64_t s_K[4], s_newK[4];
    __shared__ uint32_t s_chg;

    uint32_t* hist  = (uint32_t*)s_keys;
    uint32_t* fhist = s_glist;
    uint32_t* csum  = (uint32_t*)s_skeys;

    const int b = blockIdx.x;
    const int t = threadIdx.x;

    // ---- zero this image's output slice (replaces hipMemsetAsync; rocclr's
    // fill kernel ran at 35 GB/s and cost ~72us for 2.6MB)
    {
        float4* ob = reinterpret_cast<float4*>(out + (size_t)b * OUTFLO);
        const float4 z = make_float4(0.f, 0.f, 0.f, 0.f);
        for (int i = t; i < OUTFLO / 4; i += 1024) ob[i] = z;
    }

    // ---- init
    for (int i = t; i < 8192; i += 1024) hist[i] = 0;
    if (t < 12) s_shv[t] = 0;
    __syncthreads();

    // ---- step 1: load group maxes; coarse hist (bits>>17) + box max
    {
        const float2* gmb = gm2 + (size_t)b * NGRP;
        float wm = 0.0f;
        for (int i = t; i < NGRP; i += 1024) {
            float2 v = gmb[i];
            s_gm[i] = v.x;
            wm = fmaxf(wm, v.y);
            if (v.x > CONF_T) atomicAdd(&hist[__float_as_uint(v.x) >> 17], 1u);
        }
        #pragma unroll
        for (int m = 1; m < 64; m <<= 1) wm = fmaxf(wm, __shfl_xor(wm, m));
        if ((t & 63) == 0) s_bmaxarr[t >> 6] = wm;
    }
    __syncthreads();

    // ---- coarse crossing via suffix scan over 1024 chunk-sums
    uint32_t v8 = 0;
    #pragma unroll
    for (int k = 0; k < 8; ++k) v8 += hist[t * 8 + k];
    suffix_scan_1024(v8, t, s_wtot, csum);
    {
        uint32_t sIn = csum[t];
        uint32_t sNext = (t == 1023) ? 0u : csum[t + 1];
        if (sIn >= NSEL && sNext < NSEL) { s_shv[0] = (uint32_t)t; s_shv[1] = sNext; s_shv[2] = 1; }
    }
    __syncthreads();
    for (int i = t; i < 2048; i += 1024) fhist[i] = 0;
    if (t == 0) {
        float mx = s_bmaxarr[0];
        #pragma unroll
        for (int k = 1; k < 16; ++k) mx = fmaxf(mx, s_bmaxarr[k]);
        s_offm = mx + 1.0f;                    // jnp.max(boxes) + 1
        if (s_shv[2]) {
            uint32_t chunk = s_shv[0], run2 = s_shv[1]; int cb = -1; uint32_t ab = 0;
            for (int k = 7; k >= 0; --k) {
                uint32_t v = hist[chunk * 8 + k];
                if (cb < 0 && run2 + v >= NSEL) { cb = (int)(chunk * 8 + k); ab = run2; }
                run2 += v;
            }
            s_shv[0] = (uint32_t)cb; s_shv[1] = ab;
        }
    }
    __syncthreads();

    const uint32_t found = s_shv[2], cbin = s_shv[0], above = s_shv[1];
    // ---- fine hist on group maxes in cbin; zero keys (hist now dead)
    for (int i = t; i < MKEYS; i += 1024) s_keys[i] = 0ull;
    if (found) {
        for (int i = t; i < NGRP; i += 1024) {
            float s = s_gm[i];
            if (s > CONF_T) {
                uint32_t bits = __float_as_uint(s);
                if ((bits >> 17) == cbin) atomicAdd(&fhist[(bits >> 6) & 2047u], 1u);
            }
        }
    }
    __syncthreads();
    uint32_t fv = fhist[2 * t] + fhist[2 * t + 1];
    suffix_scan_1024(fv, t, s_wtot, csum);
    if (found) {
        uint32_t sIn = csum[t] + above;
        uint32_t sNext = ((t == 1023) ? 0u : csum[t + 1]) + above;
        if (sIn >= NSEL && sNext < NSEL) { s_shv[5] = (uint32_t)t; s_shv[6] = sNext; }
    }
    __syncthreads();
    if (t == 0) {
        if (found) {
            uint32_t pc = s_shv[5], ab2 = s_shv[6];
            uint32_t v1 = fhist[pc * 2 + 1];
            uint32_t fbin = (ab2 + v1 >= NSEL) ? (pc * 2 + 1) : (pc * 2);
            s_shv[3] = (cbin << 11) | fbin;
        } else s_shv[3] = 0;
    }
    __syncthreads();

    // ---- qualify groups (gmax >= T); fhist dead -> glist
    const uint32_t T = s_shv[3];
    for (int i = t; i < NGRP; i += 1024) {
        float s = s_gm[i];
        if (s > CONF_T && (__float_as_uint(s) >> 6) >= T) {
            uint32_t p = atomicAdd(&s_shv[8], 1u);
            if (p < 2048u) s_glist[p] = (uint32_t)i;
        }
    }
    __syncthreads();
    uint32_t ngl = s_shv[8]; if (ngl > 2048u) ngl = 2048u;

    // ---- gather candidate anchors from qualified groups only
    {
        const float4* sc4 = reinterpret_cast<const float4*>(scores + (size_t)b * NA);
        #define GATH1(s, g) { if ((s) > CONF_T) { uint32_t _b = __float_as_uint(s); \
            if ((_b >> 6) >= T) { uint32_t _p = atomicAdd(&s_shv[4], 1u); \
                if (_p < MKEYS) s_keys[_p] = ((uint64_t)_b << 32) | \
                    (uint64_t)(0xFFFFFFFFu - (uint32_t)(g)); } } }
        for (int idx = t; idx < (int)(ngl * 4); idx += 1024) {
            uint32_t gi = s_glist[idx >> 2];
            int q = idx & 3;
            float4 s4 = sc4[gi * 4 + q];
            uint32_t g0 = gi * 16 + (uint32_t)q * 4;
            GATH1(s4.x, g0)     GATH1(s4.y, g0 + 1)
            GATH1(s4.z, g0 + 2) GATH1(s4.w, g0 + 3)
        }
    }
    __syncthreads();
    uint32_t nGa = s_shv[4]; if (nGa > MKEYS) nGa = MKEYS;
    const int lim = (nGa < 256u) ? (int)nGa : 256;

    // ---- rank sort descending via readlane broadcast (keys unique via ~idx)
    {
        const int lane = t & 63;
        const uint32_t nch = (nGa + 63) >> 6;
        for (int s = 0; s < 4; ++s) {
            int kid = t + s * 1024;
            bool act = kid < (int)nGa;
            if (__ballot(act) == 0ull) continue;
            uint64_t my = act ? s_keys[kid] : ~0ull;
            uint32_t r = 0;
            for (uint32_t ch = 0; ch < nch; ++ch) {
                uint64_t kc = s_keys[ch * 64 + lane];   // pad region zeroed
                uint32_t clo = (uint32_t)kc, chi = (uint32_t)(kc >> 32);
                for (int jj = 0; jj < 64; ++jj) {
                    uint32_t olo = (uint32_t)__builtin_amdgcn_readlane((int)clo, jj);
                    uint32_t ohi = (uint32_t)__builtin_amdgcn_readlane((int)chi, jj);
                    uint64_t ok = ((uint64_t)ohi << 32) | olo;
                    r += (ok > my) ? 1u : 0u;
                }
            }
            if (act) s_skeys[r] = my;
        }
    }
    __syncthreads();

    // ---- prep first 256: offset boxes, areas, classes; init K; zero clsmask
    const float offm = s_offm;
    if (t < 256) {
        if (t < lim) {
            uint64_t key = s_skeys[t];
            uint32_t g = 0xFFFFFFFFu - (uint32_t)key;
            size_t qi = (size_t)b * NA + g;
            int c = (int)cls[qi];
            s_clsl[t] = (uint8_t)c;
            float4 rg = reinterpret_cast<const float4*>(reg)[qi];
            float4 an = reinterpret_cast<const float4*>(anch)[g];
            float x1, y1, x2, y2; decode_box(rg, an, x1, y1, x2, y2);
            float off = (float)c * offm;
            float4 bo = make_float4(x1 + off, y1 + off, x2 + off, y2 + off);
            s_boxo[t] = bo;
            s_areao[t] = (bo.z - bo.x) * (bo.w - bo.y);
        } else {
            s_clsl[t] = 0;
            s_boxo[t] = make_float4(0.f, 0.f, 0.f, 0.f);
            s_areao[t] = 0.f;
        }
    }
    if (t < 4) {
        int lo = t * 64, n = lim - lo;
        s_K[t] = (n >= 64) ? ~0ull : (n > 0 ? ((~0ull) >> (64 - n)) : 0ull);
    }
    if (t < NCLS * 4) ((uint64_t*)s_clsmask)[t] = 0ull;
    __syncthreads();

    // ---- 256x256 suppression mask, register-resident via readlane
    {
        const int wv = t >> 6, lane = t & 63;
        const int rbase = (wv & 3) * 64, c = wv >> 2;
        const int i = rbase + lane;
        float4 bi = s_boxo[i];
        float aI = s_areao[i];
        float4 vj = s_boxo[c * 64 + lane];
        float vA = s_areao[c * 64 + lane];
        uint64_t m = 0ull;
        for (int jj = 0; jj < 64; ++jj) {
            float bx1 = rlf(vj.x, jj), by1 = rlf(vj.y, jj);
            float bx2 = rlf(vj.z, jj), by2 = rlf(vj.w, jj);
            float aJ  = rlf(vA, jj);
            float ix1 = fmaxf(bi.x, bx1), iy1 = fmaxf(bi.y, by1);
            float ix2 = fminf(bi.z, bx2), iy2 = fminf(bi.w, by2);
            float inter = fmaxf(ix2 - ix1, 0.f) * fmaxf(iy2 - iy1, 0.f);
            float uni = aI + aJ - inter;
            if (uni > 0.f && inter + inter > uni) m |= (1ull << jj);
        }
        s_mask[(size_t)i * MROW + c] = m;
    }
    __syncthreads();

    // ---- Jacobi fixpoint greedy NMS (exact: stable iterate == greedy fixpoint)
    {
        const int jw = (t >> 6) & 3, jb = t & 63;
        const uint64_t below = (jb == 0) ? 0ull : ((~0ull) >> (64 - jb));
        const uint64_t* mrow = s_mask + (size_t)(t & 255) * MROW;
        for (int round = 0; round < 300; ++round) {
            bool nb = false;
            if (t < 256) {
                uint64_t dead = 0ull;
                #pragma unroll
                for (int w = 0; w < 4; ++w) {
                    uint64_t mm = mrow[w] & s_K[w];
                    if (w < jw) dead |= mm;
                    else if (w == jw) dead |= (mm & below);
                }
                nb = (dead == 0ull) && (t < lim);
            }
            uint64_t bal = __ballot(nb);
            if (t < 256 && (t & 63) == 0) s_newK[jw] = bal;
            if (t == 0) s_chg = 0;
            __syncthreads();
            if (t < 4 && s_newK[t] != s_K[t]) atomicOr(&s_chg, 1u);
            __syncthreads();
            if (!s_chg) break;
            if (t < 4) s_K[t] = s_newK[t];
            __syncthreads();
        }
    }

    // ---- per-class keep masks + counts + total keeps
    if (t < 256 && ((s_K[(t >> 6) & 3] >> (t & 63)) & 1ull))
        atomicOr(&s_clsmask[s_clsl[t]][(t >> 6) & 3], 1ull << (t & 63));
    __syncthreads();
    if (t < NCLS) {
        uint32_t n = 0;
        #pragma unroll
        for (int w = 0; w < 4; ++w) n += (uint32_t)__popcll(s_clsmask[t][w]);
        s_ccount[t] = n;
    }
    if (t == 0) {
        uint32_t n = 0;
        #pragma unroll
        for (int w = 0; w < 4; ++w) n += (uint32_t)__popcll(s_K[w]);
        s_shv[7] = n;
    }
    __syncthreads();

    // ---- parallel output of first TOPK keeps (order & slot via masked popcounts)
    {
        const int jw = (t >> 6) & 3, jb = t & 63;
        bool kept = (t < 256) && ((s_K[jw] >> jb) & 1ull);
        if (kept) {
            const uint64_t below = (jb == 0) ? 0ull : ((~0ull) >> (64 - jb));
            uint32_t ord = (uint32_t)__popcll(s_K[jw] & below);
            for (int w = 0; w < jw; ++w) ord += (uint32_t)__popcll(s_K[w]);
            if (ord < TOPK) {
                int c = (int)s_clsl[t];
                const uint64_t* cm = s_clsmask[c];
                uint32_t slot = (uint32_t)__popcll(cm[jw] & below);
                for (int w = 0; w < jw; ++w) slot += (uint32_t)__popcll(cm[w]);
                uint64_t key = s_skeys[t];
                uint32_t g = 0xFFFFFFFFu - (uint32_t)key;
                float scv = __uint_as_float((uint32_t)(key >> 32));
                size_t qi = (size_t)b * NA + g;
                float4 rg = reinterpret_cast<const float4*>(reg)[qi];
                float4 an = reinterpret_cast<const float4*>(anch)[g];
                float x1, y1, x2, y2; decode_box(rg, an, x1, y1, x2, y2);
                float* o = out + (((size_t)b * (NCLS + 1) + (size_t)(c + 1)) * TOPK + slot) * 5;
                o[0] = scv; o[1] = x1; o[2] = y1; o[3] = x2; o[4] = y2;
                s_keptbox[ord] = s_boxo[t];    // for fallback
            }
        }
    }
    __syncthreads();

    // ---- serial fallback past lim (exactness insurance; ~never taken)
    if (t == 0) {
        uint32_t nk = s_shv[7];
        if (nk < TOPK && nGa > (uint32_t)lim) {
            for (uint32_t ci = (uint32_t)lim; ci < nGa && nk < TOPK; ++ci) {
                uint64_t key = s_skeys[ci];
                uint32_t g = 0xFFFFFFFFu - (uint32_t)key;
                size_t qi = (size_t)b * NA + g;
                int c = (int)cls[qi];
                float4 rg = reinterpret_cast<const float4*>(reg)[qi];
                float4 an = reinterpret_cast<const float4*>(anch)[g];
                float x1, y1, x2, y2; decode_box(rg, an, x1, y1, x2, y2);
                float off = (float)c * offm;
                float4 bo = make_float4(x1 + off, y1 + off, x2 + off, y2 + off);
                float aB2 = (bo.z - bo.x) * (bo.w - bo.y);
                bool sup = false;
                for (uint32_t k2 = 0; k2 < nk && !sup; ++k2) {
                    float4 kb = s_keptbox[k2];
                    float aK = (kb.z - kb.x) * (kb.w - kb.y);
                    float ix1 = fmaxf(bo.x, kb.x), iy1 = fmaxf(bo.y, kb.y);
                    float ix2 = fminf(bo.z, kb.z), iy2 = fminf(bo.w, kb.w);
                    float inter = fmaxf(ix2 - ix1, 0.f) * fmaxf(iy2 - iy1, 0.f);
                    float uni = aB2 + aK - inter;
                    sup = (uni > 0.f && inter + inter > uni);
                }
                if (!sup) {
                    uint32_t slot = s_ccount[c]; s_ccount[c] = slot + 1;
                    float scv = __uint_as_float((uint32_t)(key >> 32));
                    float* o = out + (((size_t)b * (NCLS + 1) + (size_t)(c + 1)) * TOPK + slot) * 5;
                    o[0] = scv; o[1] = x1; o[2] = y1; o[3] = x2; o[4] = y2;
                    s_keptbox[nk] = bo;
                    ++nk;
                }
            }
        }
    }
}

extern "C" void kernel_launch(void* const* d_in, const int* in_sizes, int n_in,
                              void* d_out, int out_size, void* d_ws, size_t ws_size,
                              hipStream_t stream)
{
    const float* conf = (const float*)d_in[0];   // [B, A, 81] f32
    const float* reg  = (const float*)d_in[1];   // [B, A, 4]  f32
    const float* anch = (const float*)d_in[2];   // [A, 4]     f32
    float* out = (float*)d_out;                  // [B, 81, 200, 5] f32

    char* ws = (char*)d_ws;
    float* scores = (float*)ws;                                       // NB*NA f32
    float2* gm2 = (float2*)(ws + (size_t)NB * NA * 4);                // NB*NGRP float2
    unsigned char* cls = (unsigned char*)(ws + (size_t)NB * NA * 4
                                             + (size_t)NB * NGRP * 8); // NB*NA u8

    // no hipMemsetAsync: phase2 blocks zero their own output slices
    int blocks = (NB * NA) / APB;        // 6138 exact
    phase1_kernel<<<blocks, 256, 0, stream>>>(conf, reg, anch, scores, cls, gm2);
    phase2_kernel<<<NB, 1024, 0, stream>>>(reg, anch, scores, cls, gm2, out);
}

// Round 8
// 67.968 us; speedup vs baseline: 8.3111x; 1.0410x over previous
//
#include <hip/hip_runtime.h>
#include <stdint.h>

#define NCLS 80
#define TOPK 200
#define CONF_T 0.05f
#define CROPF 300.0f
#define NA 49104
#define NB 8
#define NSEL 256
#define MKEYS 4096
#define APB 64
#define CHUNK (APB * 81)
#define NGRP (NA / 16)          // 3069 16-anchor groups per image (16 | NA)
#define MROW 5                  // mask row stride in u64 (odd-ish: conflict-light)
#define OUTFLO ((NCLS + 1) * TOPK * 5)   // 81000 floats per image, % 4 == 0
#define NBLK1 ((NB * NA) / APB)          // 6138 phase1 blocks

__device__ __forceinline__ void decode_box(const float4 rg, const float4 an,
                                           float& x1, float& y1, float& x2, float& y2) {
    // anchors: (ymin, xmin, ymax, xmax); reg: (dy, dx, dh, dw)
    float yca = (an.x + an.z) * 0.5f;
    float xca = (an.y + an.w) * 0.5f;
    float ha = an.z - an.x;
    float wa = an.w - an.y;
    float w = expf(rg.w) * wa;
    float h = expf(rg.z) * ha;
    float yc = rg.x * ha + yca;
    float xc = rg.y * wa + xca;
    x1 = fmaxf(xc - w * 0.5f, 0.0f) / CROPF;
    y1 = fmaxf(yc - h * 0.5f, 0.0f) / CROPF;
    x2 = fminf(xc + w * 0.5f, CROPF - 1.0f) / CROPF;
    y2 = fminf(yc + h * 0.5f, CROPF - 1.0f) / CROPF;
}

__device__ __forceinline__ float rlf(float v, int l) {
    return __int_as_float(__builtin_amdgcn_readlane(__float_as_int(v), l));
}

// Phase 1: conf -> (scores, cls); per-16-anchor-group float2{max score, max box coord};
// ALSO stripe-zeros d_out (<=1 float4 store/thread, overlapped with the conf stream).
__global__ __launch_bounds__(256) void phase1_kernel(
    const float* __restrict__ conf, const float* __restrict__ reg,
    const float* __restrict__ anch, float* __restrict__ scores,
    unsigned char* __restrict__ cls, float2* __restrict__ gm2,
    float* __restrict__ outz)
{
    __shared__ float lds[CHUNK];
    const int blk = blockIdx.x, t = threadIdx.x;

    // ---- stripe-zero d_out (2.6MB / 1.57M threads -> at most 1 store each)
    {
        const int gid = blk * 256 + t;
        constexpr int TOT4 = NB * OUTFLO / 4;      // 162000 float4s
        if (gid < TOT4)
            reinterpret_cast<float4*>(outz)[gid] = make_float4(0.f, 0.f, 0.f, 0.f);
    }

    const float4* src = reinterpret_cast<const float4*>(conf + (size_t)blk * CHUNK);
    float4* dst = reinterpret_cast<float4*>(lds);
    for (int i = t; i < CHUNK / 4; i += 256) dst[i] = src[i];
    __syncthreads();

    const int la = t >> 2, sub = t & 3;
    const int quad = blk * APB + la;           // global anchor b*NA + a
    const float* crow = lds + la * 81;
    float best = -3.0e38f; int bc = 255;
    for (int c = sub; c <= NCLS; c += 4) {
        if (c == 0) continue;                  // background stripped
        float v = crow[c];
        if (v > best) { best = v; bc = c; }    // strict > : first-index tie-break
    }
    for (int m = 1; m <= 2; m <<= 1) {
        float ov = __shfl_xor(best, m);
        int oc = __shfl_xor(bc, m);
        if (ov > best || (ov == best && oc < bc)) { best = ov; bc = oc; }
    }
    float bmaxl = 0.0f;                        // decoded coords: y1 >= 0, safe identity
    if (sub == 0) {
        scores[quad] = 1.0f / (1.0f + expf(-best));
        cls[quad] = (unsigned char)(bc - 1);
        int a = quad % NA;
        float4 rg = reinterpret_cast<const float4*>(reg)[quad];
        float4 an = reinterpret_cast<const float4*>(anch)[a];
        float x1, y1, x2, y2; decode_box(rg, an, x1, y1, x2, y2);
        bmaxl = fmaxf(fmaxf(x1, y1), fmaxf(x2, y2));
    }
    float wbest = best;                        // group max logit (monotone -> score max)
    #pragma unroll
    for (int m = 1; m < 64; m <<= 1) {
        wbest = fmaxf(wbest, __shfl_xor(wbest, m));
        bmaxl = fmaxf(bmaxl, __shfl_xor(bmaxl, m));
    }
    if ((t & 63) == 0)
        gm2[blk * 4 + (t >> 6)] = make_float2(1.0f / (1.0f + expf(-wbest)), bmaxl);
}

// block-wide inclusive SUFFIX scan over 1024 values; result into outarr[t].
__device__ __forceinline__ void suffix_scan_1024(uint32_t v, int t,
                                                 uint32_t* wtot, uint32_t* outarr) {
    uint32_t r = v;
    const int lane = t & 63, w = t >> 6;
    #pragma unroll
    for (int m = 1; m < 64; m <<= 1) {
        uint32_t o = __shfl_down(r, m);
        if (lane + m < 64) r += o;
    }
    if (lane == 0) wtot[w] = r;
    __syncthreads();
    if (t < 16) {
        uint32_t v0 = wtot[t], x = v0;
        #pragma unroll
        for (int m = 1; m < 16; m <<= 1) {
            uint32_t o = __shfl_down(x, m);
            if (t + m < 16) x += o;
        }
        wtot[t] = x - v0;                      // exclusive suffix of wave totals
    }
    __syncthreads();
    outarr[t] = r + wtot[w];
    __syncthreads();
}

// Phase 2: one block/image. Radix-select on 3069 GROUP maxes; gather only
// qualified groups' anchors; readlane rank sort; readlane 256x256 mask build;
// Jacobi-fixpoint exact greedy NMS; popcount output; exact serial fallback.
__global__ __launch_bounds__(1024) void phase2_kernel(
    const float* __restrict__ reg, const float* __restrict__ anch,
    const float* __restrict__ scores, const unsigned char* __restrict__ cls,
    const float2* __restrict__ gm2, float* __restrict__ out)
{
    __shared__ uint64_t s_keys[MKEYS];        // 32KB  alias: hist u32[8192]
    __shared__ uint64_t s_skeys[MKEYS];       // 32KB  alias: csum u32[1024]
    __shared__ uint64_t s_mask[256 * MROW];   // 10KB
    __shared__ float4   s_boxo[256];          // 4KB
    __shared__ float    s_areao[256];
    __shared__ float    s_gm[NGRP + 3];       // 12KB group score maxes
    __shared__ uint32_t s_glist[2048];        // 8KB   alias: fhist u32[2048]
    __shared__ float4   s_keptbox[TOPK];      // fallback only
    __shared__ uint64_t s_clsmask[NCLS][4];   // keep-bit mask per class
    __shared__ uint32_t s_ccount[NCLS];
    __shared__ uint32_t s_wtot[16];
    __shared__ uint32_t s_shv[12];
    __shared__ float    s_bmaxarr[16];
    __shared__ float    s_offm;
    __shared__ uint8_t  s_clsl[256];
    __shared__ uint64_t s_K[4], s_newK[4];
    __shared__ uint32_t s_chg;

    uint32_t* hist  = (uint32_t*)s_keys;
    uint32_t* fhist = s_glist;
    uint32_t* csum  = (uint32_t*)s_skeys;

    const int b = blockIdx.x;
    const int t = threadIdx.x;

    // ---- init
    for (int i = t; i < 8192; i += 1024) hist[i] = 0;
    if (t < 12) s_shv[t] = 0;
    __syncthreads();

    // ---- step 1: load group maxes; coarse hist (bits>>17) + box max
    {
        const float2* gmb = gm2 + (size_t)b * NGRP;
        float wm = 0.0f;
        for (int i = t; i < NGRP; i += 1024) {
            float2 v = gmb[i];
            s_gm[i] = v.x;
            wm = fmaxf(wm, v.y);
            if (v.x > CONF_T) atomicAdd(&hist[__float_as_uint(v.x) >> 17], 1u);
        }
        #pragma unroll
        for (int m = 1; m < 64; m <<= 1) wm = fmaxf(wm, __shfl_xor(wm, m));
        if ((t & 63) == 0) s_bmaxarr[t >> 6] = wm;
    }
    __syncthreads();

    // ---- coarse crossing via suffix scan over 1024 chunk-sums
    uint32_t v8 = 0;
    #pragma unroll
    for (int k = 0; k < 8; ++k) v8 += hist[t * 8 + k];
    suffix_scan_1024(v8, t, s_wtot, csum);
    {
        uint32_t sIn = csum[t];
        uint32_t sNext = (t == 1023) ? 0u : csum[t + 1];
        if (sIn >= NSEL && sNext < NSEL) { s_shv[0] = (uint32_t)t; s_shv[1] = sNext; s_shv[2] = 1; }
    }
    __syncthreads();
    for (int i = t; i < 2048; i += 1024) fhist[i] = 0;
    if (t == 0) {
        float mx = s_bmaxarr[0];
        #pragma unroll
        for (int k = 1; k < 16; ++k) mx = fmaxf(mx, s_bmaxarr[k]);
        s_offm = mx + 1.0f;                    // jnp.max(boxes) + 1
        if (s_shv[2]) {
            uint32_t chunk = s_shv[0], run2 = s_shv[1]; int cb = -1; uint32_t ab = 0;
            for (int k = 7; k >= 0; --k) {
                uint32_t v = hist[chunk * 8 + k];
                if (cb < 0 && run2 + v >= NSEL) { cb = (int)(chunk * 8 + k); ab = run2; }
                run2 += v;
            }
            s_shv[0] = (uint32_t)cb; s_shv[1] = ab;
        }
    }
    __syncthreads();

    const uint32_t found = s_shv[2], cbin = s_shv[0], above = s_shv[1];
    // ---- fine hist on group maxes in cbin; zero keys (hist now dead)
    for (int i = t; i < MKEYS; i += 1024) s_keys[i] = 0ull;
    if (found) {
        for (int i = t; i < NGRP; i += 1024) {
            float s = s_gm[i];
            if (s > CONF_T) {
                uint32_t bits = __float_as_uint(s);
                if ((bits >> 17) == cbin) atomicAdd(&fhist[(bits >> 6) & 2047u], 1u);
            }
        }
    }
    __syncthreads();
    uint32_t fv = fhist[2 * t] + fhist[2 * t + 1];
    suffix_scan_1024(fv, t, s_wtot, csum);
    if (found) {
        uint32_t sIn = csum[t] + above;
        uint32_t sNext = ((t == 1023) ? 0u : csum[t + 1]) + above;
        if (sIn >= NSEL && sNext < NSEL) { s_shv[5] = (uint32_t)t; s_shv[6] = sNext; }
    }
    __syncthreads();
    if (t == 0) {
        if (found) {
            uint32_t pc = s_shv[5], ab2 = s_shv[6];
            uint32_t v1 = fhist[pc * 2 + 1];
            uint32_t fbin = (ab2 + v1 >= NSEL) ? (pc * 2 + 1) : (pc * 2);
            s_shv[3] = (cbin << 11) | fbin;
        } else s_shv[3] = 0;
    }
    __syncthreads();

    // ---- qualify groups (gmax >= T); fhist dead -> glist
    const uint32_t T = s_shv[3];
    for (int i = t; i < NGRP; i += 1024) {
        float s = s_gm[i];
        if (s > CONF_T && (__float_as_uint(s) >> 6) >= T) {
            uint32_t p = atomicAdd(&s_shv[8], 1u);
            if (p < 2048u) s_glist[p] = (uint32_t)i;
        }
    }
    __syncthreads();
    uint32_t ngl = s_shv[8]; if (ngl > 2048u) ngl = 2048u;

    // ---- gather candidate anchors from qualified groups only
    {
        const float4* sc4 = reinterpret_cast<const float4*>(scores + (size_t)b * NA);
        #define GATH1(s, g) { if ((s) > CONF_T) { uint32_t _b = __float_as_uint(s); \
            if ((_b >> 6) >= T) { uint32_t _p = atomicAdd(&s_shv[4], 1u); \
                if (_p < MKEYS) s_keys[_p] = ((uint64_t)_b << 32) | \
                    (uint64_t)(0xFFFFFFFFu - (uint32_t)(g)); } } }
        for (int idx = t; idx < (int)(ngl * 4); idx += 1024) {
            uint32_t gi = s_glist[idx >> 2];
            int q = idx & 3;
            float4 s4 = sc4[gi * 4 + q];
            uint32_t g0 = gi * 16 + (uint32_t)q * 4;
            GATH1(s4.x, g0)     GATH1(s4.y, g0 + 1)
            GATH1(s4.z, g0 + 2) GATH1(s4.w, g0 + 3)
        }
    }
    __syncthreads();
    uint32_t nGa = s_shv[4]; if (nGa > MKEYS) nGa = MKEYS;
    const int lim = (nGa < 256u) ? (int)nGa : 256;

    // ---- rank sort descending via readlane broadcast (keys unique via ~idx)
    {
        const int lane = t & 63;
        const uint32_t nch = (nGa + 63) >> 6;
        for (int s = 0; s < 4; ++s) {
            int kid = t + s * 1024;
            bool act = kid < (int)nGa;
            if (__ballot(act) == 0ull) continue;
            uint64_t my = act ? s_keys[kid] : ~0ull;
            uint32_t r = 0;
            for (uint32_t ch = 0; ch < nch; ++ch) {
                uint64_t kc = s_keys[ch * 64 + lane];   // pad region zeroed
                uint32_t clo = (uint32_t)kc, chi = (uint32_t)(kc >> 32);
                for (int jj = 0; jj < 64; ++jj) {
                    uint32_t olo = (uint32_t)__builtin_amdgcn_readlane((int)clo, jj);
                    uint32_t ohi = (uint32_t)__builtin_amdgcn_readlane((int)chi, jj);
                    uint64_t ok = ((uint64_t)ohi << 32) | olo;
                    r += (ok > my) ? 1u : 0u;
                }
            }
            if (act) s_skeys[r] = my;
        }
    }
    __syncthreads();

    // ---- prep first 256: offset boxes, areas, classes; init K; zero clsmask
    const float offm = s_offm;
    if (t < 256) {
        if (t < lim) {
            uint64_t key = s_skeys[t];
            uint32_t g = 0xFFFFFFFFu - (uint32_t)key;
            size_t qi = (size_t)b * NA + g;
            int c = (int)cls[qi];
            s_clsl[t] = (uint8_t)c;
            float4 rg = reinterpret_cast<const float4*>(reg)[qi];
            float4 an = reinterpret_cast<const float4*>(anch)[g];
            float x1, y1, x2, y2; decode_box(rg, an, x1, y1, x2, y2);
            float off = (float)c * offm;
            float4 bo = make_float4(x1 + off, y1 + off, x2 + off, y2 + off);
            s_boxo[t] = bo;
            s_areao[t] = (bo.z - bo.x) * (bo.w - bo.y);
        } else {
            s_clsl[t] = 0;
            s_boxo[t] = make_float4(0.f, 0.f, 0.f, 0.f);
            s_areao[t] = 0.f;
        }
    }
    if (t < 4) {
        int lo = t * 64, n = lim - lo;
        s_K[t] = (n >= 64) ? ~0ull : (n > 0 ? ((~0ull) >> (64 - n)) : 0ull);
    }
    if (t < NCLS * 4) ((uint64_t*)s_clsmask)[t] = 0ull;
    __syncthreads();

    // ---- 256x256 suppression mask, register-resident via readlane
    {
        const int wv = t >> 6, lane = t & 63;
        const int rbase = (wv & 3) * 64, c = wv >> 2;
        const int i = rbase + lane;
        float4 bi = s_boxo[i];
        float aI = s_areao[i];
        float4 vj = s_boxo[c * 64 + lane];
        float vA = s_areao[c * 64 + lane];
        uint64_t m = 0ull;
        for (int jj = 0; jj < 64; ++jj) {
            float bx1 = rlf(vj.x, jj), by1 = rlf(vj.y, jj);
            float bx2 = rlf(vj.z, jj), by2 = rlf(vj.w, jj);
            float aJ  = rlf(vA, jj);
            float ix1 = fmaxf(bi.x, bx1), iy1 = fmaxf(bi.y, by1);
            float ix2 = fminf(bi.z, bx2), iy2 = fminf(bi.w, by2);
            float inter = fmaxf(ix2 - ix1, 0.f) * fmaxf(iy2 - iy1, 0.f);
            float uni = aI + aJ - inter;
            if (uni > 0.f && inter + inter > uni) m |= (1ull << jj);
        }
        s_mask[(size_t)i * MROW + c] = m;
    }
    __syncthreads();

    // ---- Jacobi fixpoint greedy NMS (exact: stable iterate == greedy fixpoint)
    {
        const int jw = (t >> 6) & 3, jb = t & 63;
        const uint64_t below = (jb == 0) ? 0ull : ((~0ull) >> (64 - jb));
        const uint64_t* mrow = s_mask + (size_t)(t & 255) * MROW;
        for (int round = 0; round < 300; ++round) {
            bool nb = false;
            if (t < 256) {
                uint64_t dead = 0ull;
                #pragma unroll
                for (int w = 0; w < 4; ++w) {
                    uint64_t mm = mrow[w] & s_K[w];
                    if (w < jw) dead |= mm;
                    else if (w == jw) dead |= (mm & below);
                }
                nb = (dead == 0ull) && (t < lim);
            }
            uint64_t bal = __ballot(nb);
            if (t < 256 && (t & 63) == 0) s_newK[jw] = bal;
            if (t == 0) s_chg = 0;
            __syncthreads();
            if (t < 4 && s_newK[t] != s_K[t]) atomicOr(&s_chg, 1u);
            __syncthreads();
            if (!s_chg) break;
            if (t < 4) s_K[t] = s_newK[t];
            __syncthreads();
        }
    }

    // ---- per-class keep masks + counts + total keeps
    if (t < 256 && ((s_K[(t >> 6) & 3] >> (t & 63)) & 1ull))
        atomicOr(&s_clsmask[s_clsl[t]][(t >> 6) & 3], 1ull << (t & 63));
    __syncthreads();
    if (t < NCLS) {
        uint32_t n = 0;
        #pragma unroll
        for (int w = 0; w < 4; ++w) n += (uint32_t)__popcll(s_clsmask[t][w]);
        s_ccount[t] = n;
    }
    if (t == 0) {
        uint32_t n = 0;
        #pragma unroll
        for (int w = 0; w < 4; ++w) n += (uint32_t)__popcll(s_K[w]);
        s_shv[7] = n;
    }
    __syncthreads();

    // ---- parallel output of first TOPK keeps (order & slot via masked popcounts)
    {
        const int jw = (t >> 6) & 3, jb = t & 63;
        bool kept = (t < 256) && ((s_K[jw] >> jb) & 1ull);
        if (kept) {
            const uint64_t below = (jb == 0) ? 0ull : ((~0ull) >> (64 - jb));
            uint32_t ord = (uint32_t)__popcll(s_K[jw] & below);
            for (int w = 0; w < jw; ++w) ord += (uint32_t)__popcll(s_K[w]);
            if (ord < TOPK) {
                int c = (int)s_clsl[t];
                const uint64_t* cm = s_clsmask[c];
                uint32_t slot = (uint32_t)__popcll(cm[jw] & below);
                for (int w = 0; w < jw; ++w) slot += (uint32_t)__popcll(cm[w]);
                uint64_t key = s_skeys[t];
                uint32_t g = 0xFFFFFFFFu - (uint32_t)key;
                float scv = __uint_as_float((uint32_t)(key >> 32));
                size_t qi = (size_t)b * NA + g;
                float4 rg = reinterpret_cast<const float4*>(reg)[qi];
                float4 an = reinterpret_cast<const float4*>(anch)[g];
                float x1, y1, x2, y2; decode_box(rg, an, x1, y1, x2, y2);
                float* o = out + (((size_t)b * (NCLS + 1) + (size_t)(c + 1)) * TOPK + slot) * 5;
                o[0] = scv; o[1] = x1; o[2] = y1; o[3] = x2; o[4] = y2;
                s_keptbox[ord] = s_boxo[t];    // for fallback
            }
        }
    }
    __syncthreads();

    // ---- serial fallback past lim (exactness insurance; ~never taken)
    if (t == 0) {
        uint32_t nk = s_shv[7];
        if (nk < TOPK && nGa > (uint32_t)lim) {
            for (uint32_t ci = (uint32_t)lim; ci < nGa && nk < TOPK; ++ci) {
                uint64_t key = s_skeys[ci];
                uint32_t g = 0xFFFFFFFFu - (uint32_t)key;
                size_t qi = (size_t)b * NA + g;
                int c = (int)cls[qi];
                float4 rg = reinterpret_cast<const float4*>(reg)[qi];
                float4 an = reinterpret_cast<const float4*>(anch)[g];
                float x1, y1, x2, y2; decode_box(rg, an, x1, y1, x2, y2);
                float off = (float)c * offm;
                float4 bo = make_float4(x1 + off, y1 + off, x2 + off, y2 + off);
                float aB2 = (bo.z - bo.x) * (bo.w - bo.y);
                bool sup = false;
                for (uint32_t k2 = 0; k2 < nk && !sup; ++k2) {
                    float4 kb = s_keptbox[k2];
                    float aK = (kb.z - kb.x) * (kb.w - kb.y);
                    float ix1 = fmaxf(bo.x, kb.x), iy1 = fmaxf(bo.y, kb.y);
                    float ix2 = fminf(bo.z, kb.z), iy2 = fminf(bo.w, kb.w);
                    float inter = fmaxf(ix2 - ix1, 0.f) * fmaxf(iy2 - iy1, 0.f);
                    float uni = aB2 + aK - inter;
                    sup = (uni > 0.f && inter + inter > uni);
                }
                if (!sup) {
                    uint32_t slot = s_ccount[c]; s_ccount[c] = slot + 1;
                    float scv = __uint_as_float((uint32_t)(key >> 32));
                    float* o = out + (((size_t)b * (NCLS + 1) + (size_t)(c + 1)) * TOPK + slot) * 5;
                    o[0] = scv; o[1] = x1; o[2] = y1; o[3] = x2; o[4] = y2;
                    s_keptbox[nk] = bo;
                    ++nk;
                }
            }
        }
    }
}

extern "C" void kernel_launch(void* const* d_in, const int* in_sizes, int n_in,
                              void* d_out, int out_size, void* d_ws, size_t ws_size,
                              hipStream_t stream)
{
    const float* conf = (const float*)d_in[0];   // [B, A, 81] f32
    const float* reg  = (const float*)d_in[1];   // [B, A, 4]  f32
    const float* anch = (const float*)d_in[2];   // [A, 4]     f32
    float* out = (float*)d_out;                  // [B, 81, 200, 5] f32

    char* ws = (char*)d_ws;
    float* scores = (float*)ws;                                       // NB*NA f32
    float2* gm2 = (float2*)(ws + (size_t)NB * NA * 4);                // NB*NGRP float2
    unsigned char* cls = (unsigned char*)(ws + (size_t)NB * NA * 4
                                             + (size_t)NB * NGRP * 8); // NB*NA u8

    // d_out zeroing is striped inside phase1 (full-GPU, overlapped with conf stream)
    phase1_kernel<<<NBLK1, 256, 0, stream>>>(conf, reg, anch, scores, cls, gm2, out);
    phase2_kernel<<<NB, 1024, 0, stream>>>(reg, anch, scores, cls, gm2, out);
}